// Round 7
// baseline (25936.850 us; speedup 1.0000x reference)
//
#include <hip/hip_runtime.h>

#define B_ 8
#define H_ 8
#define DM 512
#define DH 64
#define LMAX 2048
#define COUT 2

// ---------------- JAX threefry2x32 ----------------
__device__ __forceinline__ void tf2x32(unsigned k0, unsigned k1, unsigned x0, unsigned x1,
                                       unsigned& o0, unsigned& o1) {
  unsigned ks2 = k0 ^ k1 ^ 0x1BD11BDAu;
  x0 += k0; x1 += k1;
#define RND(r) { x0 += x1; x1 = (x1 << r) | (x1 >> (32 - r)); x1 ^= x0; }
  RND(13) RND(15) RND(26) RND(6)  x0 += k1;  x1 += ks2 + 1u;
  RND(17) RND(29) RND(16) RND(24) x0 += ks2; x1 += k0 + 2u;
  RND(13) RND(15) RND(26) RND(6)  x0 += k0;  x1 += k1 + 3u;
  RND(17) RND(29) RND(16) RND(24) x0 += k1;  x1 += ks2 + 4u;
  RND(13) RND(15) RND(26) RND(6)  x0 += ks2; x1 += k0 + 5u;
#undef RND
  o0 = x0; o1 = x1;
}

// randint Variant B, partitionable (modern JAX default):
//   k1, k2 = split(folded_key)   [fold-like split: key_j = threefry(key,(0,j))]
//   lower_bits = random_bits(k2, 32, (L,U)) = o0^o1 of threefry(k2,(0,p))
//   span L pow2 -> multiplier==0 -> idx = lower_bits & (L-1)
__global__ void idx_kernel(int* __restrict__ idxArr, int L, int U, int layer) {
  int p = blockIdx.x * 256 + threadIdx.x;
  int half = L * U;
  if (p >= half) return;
  unsigned fk0, fk1, k20, k21, o0, o1;
  tf2x32(0u, 42u, 0u, (unsigned)layer, fk0, fk1);   // fold_in(key(42), layer)
  tf2x32(fk0, fk1, 0u, 1u, k20, k21);               // k2 = split(key)[1]
  tf2x32(k20, k21, 0u, (unsigned)p, o0, o1);        // bits[p], counter (0,p)
  idxArr[p] = (int)((o0 ^ o1) & (unsigned)(L - 1));
}

// ---------------- token embed + positional encoding ----------------
__global__ void embed_kernel(const float* __restrict__ xe, const float* __restrict__ tw,
                             float* __restrict__ X) {
  int i = blockIdx.x * 256 + threadIdx.x;          // B*LMAX*DM
  int c = i % DM;
  int l = (i / DM) % LMAX;
  int b = i / (DM * LMAX);
  int lm = (l + LMAX - 1) & (LMAX - 1);
  int lp = (l + 1) & (LMAX - 1);
  const float* xb = xe + b * LMAX;
  float tok = tw[c * 3 + 0] * xb[lm] + tw[c * 3 + 1] * xb[l] + tw[c * 3 + 2] * xb[lp];
  float freq = expf(-(float)(c & ~1) * (9.210340371976184f / 512.0f));
  float ang = (float)l * freq;
  float pe = (c & 1) ? cosf(ang) : sinf(ang);
  X[i] = tok + pe;
}

// ---------------- GEMM: C[M,N] (+)= A[M,K] @ W[N,K]^T + bias ----------------
// ACT: 1=exact gelu. QKV: write (h,l,d) layout (per-b). ACC: C += (residual fuse).
template <int ACT, int QKV, int ACC>
__global__ void gemm_kernel(const float* __restrict__ A, const float* __restrict__ W,
                            const float* __restrict__ bias, float* __restrict__ C,
                            int M, int N, int K, int L) {
  __shared__ float As[16][64];
  __shared__ float Bs[16][68];
  int tid = threadIdx.x;
  int tx = tid & 15, ty = tid >> 4;
  int n0 = blockIdx.x * 64, m0 = blockIdx.y * 64;
  float acc[4][4] = {};
  for (int k0 = 0; k0 < K; k0 += 16) {
    for (int t = tid; t < 1024; t += 256) {
      int m = t >> 4, kk = t & 15;
      As[kk][m] = A[(size_t)(m0 + m) * K + k0 + kk];
    }
    for (int t = tid; t < 1024; t += 256) {
      int n = t >> 4, kk = t & 15;
      Bs[kk][n] = W[(size_t)(n0 + n) * K + k0 + kk];
    }
    __syncthreads();
#pragma unroll
    for (int kk = 0; kk < 16; ++kk) {
      float a[4], bb[4];
#pragma unroll
      for (int i = 0; i < 4; ++i) a[i] = As[kk][ty * 4 + i];
#pragma unroll
      for (int j = 0; j < 4; ++j) bb[j] = Bs[kk][tx * 4 + j];
#pragma unroll
      for (int i = 0; i < 4; ++i)
#pragma unroll
        for (int j = 0; j < 4; ++j) acc[i][j] += a[i] * bb[j];
    }
    __syncthreads();
  }
#pragma unroll
  for (int i = 0; i < 4; ++i) {
    int row = m0 + ty * 4 + i;
#pragma unroll
    for (int j = 0; j < 4; ++j) {
      int col = n0 + tx * 4 + j;
      float v = acc[i][j] + bias[col];
      if (ACT == 1) v = 0.5f * v * (1.0f + erff(v * 0.70710678118654752f));
      if (QKV) {
        int h = col >> 6, d = col & 63;
        C[((size_t)h * L + row) * DH + d] = v;       // per-b: row==l
      } else if (ACC) {
        C[(size_t)row * N + col] += v;
      } else {
        C[(size_t)row * N + col] = v;
      }
    }
  }
}

// ---------------- sampled qk -> M = max_u - mean_u (per-b) ----------------
__global__ void qkM_kernel(const float* __restrict__ Q, const float* __restrict__ Kd,
                           const int* __restrict__ idxArr, float* __restrict__ Mout,
                           int L, int U) {
  int lane = threadIdx.x & 63, wv = threadIdx.x >> 6;
  int row = blockIdx.x * 4 + wv;                    // over H*L
  int l = row % L, h = row / L;
  float qd = Q[((size_t)h * L + l) * DH + lane];
  float mx = -1e30f, sm = 0.f;
  for (int u = 0; u < U; ++u) {
    int ki = idxArr[l * U + u];
    float p = qd * Kd[((size_t)h * L + ki) * DH + lane];
#pragma unroll
    for (int o = 32; o >= 1; o >>= 1) p += __shfl_xor(p, o, 64);
    mx = fmaxf(mx, p);
    sm += p;
  }
  if (lane == 0) Mout[row] = mx - sm / (float)U;
}

// ---------------- top-U per h (set semantics, low-index tie-break) ----------------
__global__ void topk_kernel(const float* __restrict__ M, int* __restrict__ top, int L, int U) {
  __shared__ float vals[LMAX];
  __shared__ float rv[256];
  __shared__ int ri[256];
  int h = blockIdx.x, tid = threadIdx.x;
  for (int j = tid; j < L; j += 256) vals[j] = M[(size_t)h * L + j];
  __syncthreads();
  for (int u = 0; u < U; ++u) {
    float bv = -1e30f; int bi = L;
    for (int j = tid; j < L; j += 256) {
      float v = vals[j];
      if (v > bv) { bv = v; bi = j; }
    }
    rv[tid] = bv; ri[tid] = bi;
    __syncthreads();
    for (int s = 128; s >= 1; s >>= 1) {
      if (tid < s) {
        float ov = rv[tid + s]; int oi = ri[tid + s];
        if (ov > rv[tid] || (ov == rv[tid] && oi < ri[tid])) { rv[tid] = ov; ri[tid] = oi; }
      }
      __syncthreads();
    }
    if (tid == 0) { top[h * U + u] = ri[0]; vals[ri[0]] = -1e30f; }
    __syncthreads();
  }
}

// ---------------- v mean over L per (h,d) (per-b) ----------------
__global__ void vmean_kernel(const float* __restrict__ V, float* __restrict__ VM, int L) {
  __shared__ float red[256];
  int h = blockIdx.x, tid = threadIdx.x, d = tid & 63, sq = tid >> 6;
  float s = 0.f;
  for (int l = sq; l < L; l += 4) s += V[((size_t)h * L + l) * DH + d];
  red[tid] = s;
  __syncthreads();
  if (sq == 0) VM[h * DH + d] = (red[d] + red[d + 64] + red[d + 128] + red[d + 192]) / (float)L;
}

// ---------------- fill ctx slice (L,DM) with v-mean (per-b) ----------------
__global__ void fill_kernel(const float* __restrict__ VM, float* __restrict__ O, int L) {
  int i = blockIdx.x * 256 + threadIdx.x;           // L*DM
  O[i] = VM[i % DM];
}

// ---------------- full attention for selected queries (per-b) ----------------
__global__ void attn_update_kernel(const float* __restrict__ Q, const float* __restrict__ Kd,
                                   const float* __restrict__ V, const int* __restrict__ top,
                                   float* __restrict__ O, int L, int U) {
  __shared__ float qrow[DH];
  __shared__ float sc[LMAX];
  __shared__ float red[256];
  int blk = blockIdx.x;             // h*U + u
  int u = blk % U, h = blk / U;
  int tid = threadIdx.x, lane = tid & 63, wv = tid >> 6;
  int lstar = top[h * U + u];
  if (tid < DH) qrow[tid] = Q[((size_t)h * L + lstar) * DH + tid];
  __syncthreads();
  float qd = qrow[lane];
  float lmax = -1e30f;
  for (int j = wv; j < L; j += 4) {
    float p = qd * Kd[((size_t)h * L + j) * DH + lane];
#pragma unroll
    for (int o = 32; o >= 1; o >>= 1) p += __shfl_xor(p, o, 64);
    p *= 0.125f;                    // 1/sqrt(64)
    if (lane == 0) sc[j] = p;
    lmax = fmaxf(lmax, p);
  }
  red[tid] = lmax;
  __syncthreads();
  for (int s = 128; s >= 1; s >>= 1) {
    if (tid < s) red[tid] = fmaxf(red[tid], red[tid + s]);
    __syncthreads();
  }
  float mx = red[0];
  __syncthreads();
  float lsum = 0.f;
  for (int j = tid; j < L; j += 256) {
    float e = expf(sc[j] - mx);
    sc[j] = e;
    lsum += e;
  }
  red[tid] = lsum;
  __syncthreads();
  for (int s = 128; s >= 1; s >>= 1) {
    if (tid < s) red[tid] += red[tid + s];
    __syncthreads();
  }
  float inv = 1.0f / red[0];
  __syncthreads();
  int d = tid & 63, sq = tid >> 6;
  float o = 0.f;
  for (int j = sq; j < L; j += 4) o += sc[j] * V[((size_t)h * L + j) * DH + d];
  red[tid] = o;
  __syncthreads();
  if (sq == 0) {
    float tot = red[d] + red[d + 64] + red[d + 128] + red[d + 192];
    O[(size_t)lstar * DM + h * DH + d] = tot * inv;
  }
}

// ---------------- x = LayerNorm(x) in place ----------------
__global__ void ln_kernel(float* __restrict__ X, const float* __restrict__ g,
                          const float* __restrict__ be) {
  __shared__ float red[256];
  int row = blockIdx.x, tid = threadIdx.x;
  size_t base = (size_t)row * DM;
  float t0 = X[base + tid];
  float t1 = X[base + tid + 256];
  red[tid] = t0 + t1;
  __syncthreads();
  for (int s = 128; s >= 1; s >>= 1) { if (tid < s) red[tid] += red[tid + s]; __syncthreads(); }
  float mu = red[0] / 512.0f;
  __syncthreads();
  float d0 = t0 - mu, d1 = t1 - mu;
  red[tid] = d0 * d0 + d1 * d1;
  __syncthreads();
  for (int s = 128; s >= 1; s >>= 1) { if (tid < s) red[tid] += red[tid + s]; __syncthreads(); }
  float rstd = 1.0f / sqrtf(red[0] / 512.0f + 1e-5f);
  X[base + tid] = d0 * rstd * g[tid] + be[tid];
  X[base + tid + 256] = d1 * rstd * g[tid + 256] + be[tid + 256];
}

// ---------------- distil conv (k=3, circular) + BN + ELU ----------------
__global__ void conv_kernel(const float* __restrict__ X, const float* __restrict__ w,
                            const float* __restrict__ cb, const float* __restrict__ g,
                            const float* __restrict__ be, float* __restrict__ Y, int L) {
  __shared__ float As[16][68];   // 66 rows used
  __shared__ float W0[16][64], W1s[16][64], W2s[16][64];
  int tid = threadIdx.x, tx = tid & 15, ty = tid >> 4;
  int n0 = blockIdx.x * 64, m0 = blockIdx.y * 64;
  int b = m0 / L, l0 = m0 % L;
  float acc[4][4] = {};
  for (int k0 = 0; k0 < DM; k0 += 16) {
    for (int t = tid; t < 66 * 16; t += 256) {
      int m = t >> 4, kk = t & 15;
      int l = (l0 - 1 + m + L) % L;
      As[kk][m] = X[((size_t)b * L + l) * DM + k0 + kk];
    }
    for (int t = tid; t < 1024; t += 256) {
      int n = t >> 4, kk = t & 15;
      const float* wp = w + ((size_t)(n0 + n) * DM + (k0 + kk)) * 3;
      W0[kk][n] = wp[0];
      W1s[kk][n] = wp[1];
      W2s[kk][n] = wp[2];
    }
    __syncthreads();
#pragma unroll
    for (int kk = 0; kk < 16; ++kk) {
      float a[6];
#pragma unroll
      for (int i = 0; i < 6; ++i) a[i] = As[kk][ty * 4 + i];
      float b0[4], b1[4], b2v[4];
#pragma unroll
      for (int j = 0; j < 4; ++j) {
        b0[j] = W0[kk][tx * 4 + j];
        b1[j] = W1s[kk][tx * 4 + j];
        b2v[j] = W2s[kk][tx * 4 + j];
      }
#pragma unroll
      for (int i = 0; i < 4; ++i)
#pragma unroll
        for (int j = 0; j < 4; ++j)
          acc[i][j] += a[i] * b0[j] + a[i + 1] * b1[j] + a[i + 2] * b2v[j];
    }
    __syncthreads();
  }
  const float invs = 0.9999950000374997f;  // 1/sqrt(1+1e-5)
#pragma unroll
  for (int i = 0; i < 4; ++i) {
    int row = m0 + ty * 4 + i;
#pragma unroll
    for (int j = 0; j < 4; ++j) {
      int c = n0 + tx * 4 + j;
      float z = acc[i][j] + cb[c];
      z = z * invs * g[c] + be[c];
      z = z > 0.f ? z : expm1f(z);
      Y[(size_t)row * DM + c] = z;
    }
  }
}

// ---------------- maxpool k=3 s=2 pad=1 along L ----------------
__global__ void pool_kernel(const float* __restrict__ Y, float* __restrict__ X, int L2) {
  int i = blockIdx.x * 256 + threadIdx.x;  // B*L2*DM
  int c = i % DM;
  int t = (i / DM) % L2;
  int b = i / (DM * L2);
  int L = L2 * 2;
  const float* yb = Y + (size_t)b * L * DM + c;
  float m = fmaxf(yb[(size_t)(2 * t) * DM], yb[(size_t)(2 * t + 1) * DM]);
  if (t > 0) m = fmaxf(m, yb[(size_t)(2 * t - 1) * DM]);
  X[i] = m;
}

// ---------------- column max over L ----------------
__global__ void colmax_kernel(const float* __restrict__ X, float* __restrict__ mc, int L) {
  int i = blockIdx.x * 256 + threadIdx.x;  // B*DM
  int b = i / DM, c = i % DM;
  float m = -1e30f;
  for (int l = 0; l < L; ++l) m = fmaxf(m, X[((size_t)b * L + l) * DM + c]);
  mc[i] = m;
}

// ---------------- final projection ----------------
__global__ void proj_kernel(const float* __restrict__ mc, const float* __restrict__ pw,
                            const float* __restrict__ pb, float* __restrict__ out) {
  __shared__ float red[256];
  int bo = blockIdx.x, b = bo / COUT, o = bo % COUT, tid = threadIdx.x;
  float s = mc[b * DM + tid] * pw[o * DM + tid] +
            mc[b * DM + tid + 256] * pw[o * DM + tid + 256];
  red[tid] = s;
  __syncthreads();
  for (int st = 128; st >= 1; st >>= 1) { if (tid < st) red[tid] += red[tid + st]; __syncthreads(); }
  if (tid == 0) out[bo] = red[0] + pb[o];
}

extern "C" void kernel_launch(void* const* d_in, const int* in_sizes, int n_in,
                              void* d_out, int out_size, void* d_ws, size_t ws_size,
                              hipStream_t stream) {
  (void)in_sizes; (void)n_in; (void)out_size; (void)ws_size;
  // setup_inputs() dict order: x_enc, tok_w, Wq, Wk, Wv, Wo, bq, bk, bv, bo,
  // W1, b1, W2, b2, ln1_g, ln1_b, ln2_g, ln2_b, dc_w, dc_b, bn_g, bn_b,
  // lnf_g, lnf_b, proj_w, proj_b   (Wo at index 5 — BEFORE the biases!)
  // All inputs/output are float32.
  const float* xe   = (const float*)d_in[0];
  const float* tw   = (const float*)d_in[1];
  const float* Wq   = (const float*)d_in[2];
  const float* Wk   = (const float*)d_in[3];
  const float* Wv   = (const float*)d_in[4];
  const float* Wo   = (const float*)d_in[5];
  const float* bq   = (const float*)d_in[6];
  const float* bk   = (const float*)d_in[7];
  const float* bv   = (const float*)d_in[8];
  const float* bo   = (const float*)d_in[9];
  const float* W1   = (const float*)d_in[10];
  const float* b1   = (const float*)d_in[11];
  const float* W2   = (const float*)d_in[12];
  const float* b2   = (const float*)d_in[13];
  const float* ln1g = (const float*)d_in[14];
  const float* ln1b = (const float*)d_in[15];
  const float* ln2g = (const float*)d_in[16];
  const float* ln2b = (const float*)d_in[17];
  const float* dcw  = (const float*)d_in[18];
  const float* dcb  = (const float*)d_in[19];
  const float* bng  = (const float*)d_in[20];
  const float* bnb  = (const float*)d_in[21];
  const float* lnfg = (const float*)d_in[22];
  const float* lnfb = (const float*)d_in[23];
  const float* pw   = (const float*)d_in[24];
  const float* pb   = (const float*)d_in[25];
  float* out = (float*)d_out;

  // workspace: ~78 MB total
  float* Wf = (float*)d_ws;
  const size_t NB  = (size_t)B_ * LMAX * DM;   // 8,388,608
  const size_t NHB = (size_t)H_ * LMAX * DH;   // 1,048,576 (per-b QKV)
  float* X   = Wf;
  float* T   = X + NB;
  float* Qb  = T + NB;
  float* Kb  = Qb + NHB;
  float* Vb  = Kb + NHB;
  int*   IDX = (int*)(Vb + NHB);               // <= 81,920
  float* Mv  = (float*)IDX + 81920;            // H*L <= 16,384
  int*   TOP = (int*)(Mv + 16384);             // H*U <= 320 (pad 1024)
  float* VM  = (float*)TOP + 1024;             // H*DH = 512
  float* MC  = VM + 512;                       // B*DM = 4,096

  embed_kernel<<<B_ * LMAX * DM / 256, 256, 0, stream>>>(xe, tw, X);

  int L = LMAX;
  for (int i = 0; i < 3; ++i) {
    int U = (i == 0) ? 40 : 35;  // FACTOR * ceil(ln L)
    int Mrows = B_ * L;
    dim3 ggb(DM / 64, L / 64);       // per-b gemm
    dim3 gg(DM / 64, Mrows / 64);    // full-batch gemm
    size_t wOff = (size_t)i * DM * DM;

    idx_kernel<<<(L * U + 255) / 256, 256, 0, stream>>>(IDX, L, U, i);

    for (int b = 0; b < B_; ++b) {
      const float* Xb = X + (size_t)b * L * DM;
      float* Tb = T + (size_t)b * L * DM;
      gemm_kernel<0, 1, 0><<<ggb, 256, 0, stream>>>(Xb, Wq + wOff, bq + i * DM, Qb, L, DM, DM, L);
      gemm_kernel<0, 1, 0><<<ggb, 256, 0, stream>>>(Xb, Wk + wOff, bk + i * DM, Kb, L, DM, DM, L);
      gemm_kernel<0, 1, 0><<<ggb, 256, 0, stream>>>(Xb, Wv + wOff, bv + i * DM, Vb, L, DM, DM, L);
      qkM_kernel<<<H_ * L / 4, 256, 0, stream>>>(Qb, Kb, IDX, Mv, L, U);
      topk_kernel<<<H_, 256, 0, stream>>>(Mv, TOP, L, U);
      vmean_kernel<<<H_, 256, 0, stream>>>(Vb, VM, L);
      fill_kernel<<<L * DM / 256, 256, 0, stream>>>(VM, Tb, L);
      attn_update_kernel<<<H_ * U, 256, 0, stream>>>(Qb, Kb, Vb, TOP, Tb, L, U);
    }

    // X += ctx @ Wo^T + bo ; LN
    gemm_kernel<0, 0, 1><<<gg, 256, 0, stream>>>(T, Wo + wOff, bo + i * DM, X, Mrows, DM, DM, L);
    ln_kernel<<<Mrows, 256, 0, stream>>>(X, ln1g + i * DM, ln1b + i * DM);
    // FFN: T = gelu(X@W1^T+b1); X += T@W2^T+b2 ; LN
    gemm_kernel<1, 0, 0><<<gg, 256, 0, stream>>>(X, W1 + wOff, b1 + i * DM, T, Mrows, DM, DM, L);
    gemm_kernel<0, 0, 1><<<gg, 256, 0, stream>>>(T, W2 + wOff, b2 + i * DM, X, Mrows, DM, DM, L);
    ln_kernel<<<Mrows, 256, 0, stream>>>(X, ln2g + i * DM, ln2b + i * DM);

    if (i < 2) {
      conv_kernel<<<gg, 256, 0, stream>>>(X, dcw + (size_t)i * DM * DM * 3, dcb + i * DM,
                                          bng + i * DM, bnb + i * DM, T, L);
      L >>= 1;
      pool_kernel<<<B_ * L * DM / 256, 256, 0, stream>>>(T, X, L);
    }
  }

  ln_kernel<<<B_ * L, 256, 0, stream>>>(X, lnfg, lnfb);
  colmax_kernel<<<B_ * DM / 256, 256, 0, stream>>>(X, MC, L);
  proj_kernel<<<B_ * COUT, 256, 0, stream>>>(MC, pw, pb, out);
}

// Round 8
// 4774.629 us; speedup vs baseline: 5.4322x; 5.4322x over previous
//
#include <hip/hip_runtime.h>

#define B_ 8
#define H_ 8
#define DM 512
#define DH 64
#define LMAX 2048
#define COUT 2

// ---------------- JAX threefry2x32 ----------------
__device__ __forceinline__ void tf2x32(unsigned k0, unsigned k1, unsigned x0, unsigned x1,
                                       unsigned& o0, unsigned& o1) {
  unsigned ks2 = k0 ^ k1 ^ 0x1BD11BDAu;
  x0 += k0; x1 += k1;
#define RND(r) { x0 += x1; x1 = (x1 << r) | (x1 >> (32 - r)); x1 ^= x0; }
  RND(13) RND(15) RND(26) RND(6)  x0 += k1;  x1 += ks2 + 1u;
  RND(17) RND(29) RND(16) RND(24) x0 += ks2; x1 += k0 + 2u;
  RND(13) RND(15) RND(26) RND(6)  x0 += k0;  x1 += k1 + 3u;
  RND(17) RND(29) RND(16) RND(24) x0 += k1;  x1 += ks2 + 4u;
  RND(13) RND(15) RND(26) RND(6)  x0 += ks2; x1 += k0 + 5u;
#undef RND
  o0 = x0; o1 = x1;
}

// VERIFIED (R7, absmax 0.0): Variant B partitionable. DO NOT TOUCH.
__global__ void idx_kernel(int* __restrict__ idxArr, int L, int U, int layer) {
  int p = blockIdx.x * 256 + threadIdx.x;
  int half = L * U;
  if (p >= half) return;
  unsigned fk0, fk1, k20, k21, o0, o1;
  tf2x32(0u, 42u, 0u, (unsigned)layer, fk0, fk1);   // fold_in(key(42), layer)
  tf2x32(fk0, fk1, 0u, 1u, k20, k21);               // k2 = split(key)[1]
  tf2x32(k20, k21, 0u, (unsigned)p, o0, o1);        // bits[p], counter (0,p)
  idxArr[p] = (int)((o0 ^ o1) & (unsigned)(L - 1));
}

// ---------------- token embed + positional encoding ----------------
__global__ void embed_kernel(const float* __restrict__ xe, const float* __restrict__ tw,
                             float* __restrict__ X) {
  int i = blockIdx.x * 256 + threadIdx.x;          // B*LMAX*DM
  int c = i % DM;
  int l = (i / DM) % LMAX;
  int b = i / (DM * LMAX);
  int lm = (l + LMAX - 1) & (LMAX - 1);
  int lp = (l + 1) & (LMAX - 1);
  const float* xb = xe + b * LMAX;
  float tok = tw[c * 3 + 0] * xb[lm] + tw[c * 3 + 1] * xb[l] + tw[c * 3 + 2] * xb[lp];
  float freq = expf(-(float)(c & ~1) * (9.210340371976184f / 512.0f));
  float ang = (float)l * freq;
  float pe = (c & 1) ? cosf(ang) : sinf(ang);
  X[i] = tok + pe;
}

// ---------------- tiled GEMM: C[M,512] (+)= A @ W^T + bias ----------------
// BM=128, BN=64, BK=16, 256 thr, 8x4 per thread. A row stride = DM (512).
// W row stride = Ktot. ACT=gelu, QKV=(b,h,l,d) write, ACC=+=, CONV=3-tap circular K=1536.
template <int ACT, int QKV, int ACC, int CONV>
__global__ __launch_bounds__(256) void tgemm(const float* __restrict__ A,
                                             const float* __restrict__ W,
                                             const float* __restrict__ bias,
                                             float* __restrict__ C, int L, int Ktot) {
  __shared__ float As[16][132];
  __shared__ float Bs[16][68];
  int tid = threadIdx.x;
  int n0 = blockIdx.x * 64, m0 = blockIdx.y * 128;
  int tx = tid & 15, ty = tid >> 4;
  float acc[8][4] = {};
  for (int k0 = 0; k0 < Ktot; k0 += 16) {
    int tap = 0, kcol = k0;
    if (CONV) { tap = k0 >> 9; kcol = k0 & 511; }
#pragma unroll
    for (int i = 0; i < 2; ++i) {
      int idx = tid + i * 256;
      int m = idx >> 2, kg = idx & 3;
      int row = m0 + m;
      const float* ap;
      if (CONV) {
        int b = row / L, l = row - b * L;
        int le = l + tap - 1;
        le = (le < 0) ? le + L : (le >= L ? le - L : le);
        ap = A + ((size_t)(b * L + le) * DM + kcol + kg * 4);
      } else {
        ap = A + ((size_t)row * DM + k0 + kg * 4);
      }
      float4 v = *(const float4*)ap;
      As[kg * 4 + 0][m] = v.x; As[kg * 4 + 1][m] = v.y;
      As[kg * 4 + 2][m] = v.z; As[kg * 4 + 3][m] = v.w;
    }
    {
      int n = tid >> 2, kg = tid & 3;
      float4 v = *(const float4*)(W + ((size_t)(n0 + n) * Ktot + k0 + kg * 4));
      Bs[kg * 4 + 0][n] = v.x; Bs[kg * 4 + 1][n] = v.y;
      Bs[kg * 4 + 2][n] = v.z; Bs[kg * 4 + 3][n] = v.w;
    }
    __syncthreads();
#pragma unroll
    for (int kk = 0; kk < 16; ++kk) {
      float a[8], b4[4];
#pragma unroll
      for (int i2 = 0; i2 < 8; ++i2) a[i2] = As[kk][ty * 8 + i2];
#pragma unroll
      for (int j = 0; j < 4; ++j) b4[j] = Bs[kk][tx * 4 + j];
#pragma unroll
      for (int i2 = 0; i2 < 8; ++i2)
#pragma unroll
        for (int j = 0; j < 4; ++j) acc[i2][j] += a[i2] * b4[j];
    }
    __syncthreads();
  }
#pragma unroll
  for (int i2 = 0; i2 < 8; ++i2) {
    int row = m0 + ty * 8 + i2;
#pragma unroll
    for (int j = 0; j < 4; ++j) {
      int col = n0 + tx * 4 + j;
      float v = acc[i2][j];
      if (!CONV) v += bias[col];
      if (ACT) v = 0.5f * v * (1.0f + erff(v * 0.70710678118654752f));
      if (QKV) {
        int b = row / L, l = row - b * L;
        int h = col >> 6, d = col & 63;
        C[(((size_t)b * H_ + h) * L + l) * DH + d] = v;
      } else if (ACC) {
        C[(size_t)row * DM + col] += v;
      } else {
        C[(size_t)row * DM + col] = v;
      }
    }
  }
}

// ---------------- conv weight transpose: Wt[n][tap*512+k] = w[n][k][tap] ----------------
__global__ void wt_kernel(const float* __restrict__ w, float* __restrict__ Wt) {
  int i = blockIdx.x * 256 + threadIdx.x;   // 512*1536
  int n = i / 1536, r = i - n * 1536, tap = r >> 9, k = r & 511;
  Wt[i] = w[((size_t)n * DM + k) * 3 + tap];
}

// ---------------- conv epilogue: (y+cb)*invs*g+be, ELU ----------------
__global__ void bnelu_kernel(float* __restrict__ Y, const float* __restrict__ cb,
                             const float* __restrict__ g, const float* __restrict__ be) {
  int i = blockIdx.x * 256 + threadIdx.x;
  int c = i % DM;
  const float invs = 0.9999950000374997f;  // 1/sqrt(1+1e-5)
  float z = Y[i] + cb[c];
  z = z * invs * g[c] + be[c];
  Y[i] = z > 0.f ? z : expm1f(z);
}

// ---------------- sampled qk -> M = max_u - mean_u (bh over group) ----------------
__global__ void qkM_kernel(const float* __restrict__ Q, const float* __restrict__ Kd,
                           const int* __restrict__ idxArr, float* __restrict__ Mout,
                           int L, int U) {
  int lane = threadIdx.x & 63, wv = threadIdx.x >> 6;
  int row = blockIdx.x * 4 + wv;                    // over g*H*L
  int l = row % L, bh = row / L;
  float qd = Q[((size_t)bh * L + l) * DH + lane];
  float mx = -1e30f, sm = 0.f;
  for (int u = 0; u < U; ++u) {
    int ki = idxArr[l * U + u];
    float p = qd * Kd[((size_t)bh * L + ki) * DH + lane];
#pragma unroll
    for (int o = 32; o >= 1; o >>= 1) p += __shfl_xor(p, o, 64);
    mx = fmaxf(mx, p);
    sm += p;
  }
  if (lane == 0) Mout[row] = mx - sm / (float)U;
}

// ---------------- top-U per bh (set semantics) ----------------
__global__ void topk_kernel(const float* __restrict__ M, int* __restrict__ top, int L, int U) {
  __shared__ float vals[LMAX];
  __shared__ float rv[256];
  __shared__ int ri[256];
  int bh = blockIdx.x, tid = threadIdx.x;
  for (int j = tid; j < L; j += 256) vals[j] = M[(size_t)bh * L + j];
  __syncthreads();
  for (int u = 0; u < U; ++u) {
    float bv = -1e30f; int bi = L;
    for (int j = tid; j < L; j += 256) {
      float v = vals[j];
      if (v > bv) { bv = v; bi = j; }
    }
    rv[tid] = bv; ri[tid] = bi;
    __syncthreads();
    for (int s = 128; s >= 1; s >>= 1) {
      if (tid < s) {
        float ov = rv[tid + s]; int oi = ri[tid + s];
        if (ov > rv[tid] || (ov == rv[tid] && oi < ri[tid])) { rv[tid] = ov; ri[tid] = oi; }
      }
      __syncthreads();
    }
    if (tid == 0) { top[bh * U + u] = ri[0]; vals[ri[0]] = -1e30f; }
    __syncthreads();
  }
}

// ---------------- v mean over L per (bh,d) ----------------
__global__ void vmean_kernel(const float* __restrict__ V, float* __restrict__ VM, int L) {
  __shared__ float red[256];
  int bh = blockIdx.x, tid = threadIdx.x, d = tid & 63, sq = tid >> 6;
  float s = 0.f;
  for (int l = sq; l < L; l += 4) s += V[((size_t)bh * L + l) * DH + d];
  red[tid] = s;
  __syncthreads();
  if (sq == 0) VM[bh * DH + d] = (red[d] + red[d + 64] + red[d + 128] + red[d + 192]) / (float)L;
}

// ---------------- fill ctx (g,L,DM) with v-mean ----------------
__global__ void fill_kernel(const float* __restrict__ VM, float* __restrict__ O, int L) {
  size_t i = (size_t)blockIdx.x * 256 + threadIdx.x;  // g*L*DM
  int c = (int)(i % DM);
  int b = (int)(i / ((size_t)L * DM));
  O[i] = VM[b * DM + c];   // VM laid [g][H*DH=512]
}

// ---------------- full attention for selected queries ----------------
__global__ void attn_update_kernel(const float* __restrict__ Q, const float* __restrict__ Kd,
                                   const float* __restrict__ V, const int* __restrict__ top,
                                   float* __restrict__ O, int L, int U) {
  __shared__ float qrow[DH];
  __shared__ float sc[LMAX];
  __shared__ float red[256];
  int blk = blockIdx.x;             // bh*U + u
  int u = blk % U, bh = blk / U;
  int tid = threadIdx.x, lane = tid & 63, wv = tid >> 6;
  int lstar = top[bh * U + u];
  if (tid < DH) qrow[tid] = Q[((size_t)bh * L + lstar) * DH + tid];
  __syncthreads();
  float qd = qrow[lane];
  float lmax = -1e30f;
  for (int j = wv; j < L; j += 4) {
    float p = qd * Kd[((size_t)bh * L + j) * DH + lane];
#pragma unroll
    for (int o = 32; o >= 1; o >>= 1) p += __shfl_xor(p, o, 64);
    p *= 0.125f;                    // 1/sqrt(64)
    if (lane == 0) sc[j] = p;
    lmax = fmaxf(lmax, p);
  }
  red[tid] = lmax;
  __syncthreads();
  for (int s = 128; s >= 1; s >>= 1) {
    if (tid < s) red[tid] = fmaxf(red[tid], red[tid + s]);
    __syncthreads();
  }
  float mx = red[0];
  __syncthreads();
  float lsum = 0.f;
  for (int j = tid; j < L; j += 256) {
    float e = expf(sc[j] - mx);
    sc[j] = e;
    lsum += e;
  }
  red[tid] = lsum;
  __syncthreads();
  for (int s = 128; s >= 1; s >>= 1) {
    if (tid < s) red[tid] += red[tid + s];
    __syncthreads();
  }
  float inv = 1.0f / red[0];
  __syncthreads();
  int d = tid & 63, sq = tid >> 6;
  float o = 0.f;
  for (int j = sq; j < L; j += 4) o += sc[j] * V[((size_t)bh * L + j) * DH + d];
  red[tid] = o;
  __syncthreads();
  if (sq == 0) {
    float tot = red[d] + red[d + 64] + red[d + 128] + red[d + 192];
    int b = bh / H_, h = bh % H_;
    O[((size_t)b * L + lstar) * DM + h * DH + d] = tot * inv;
  }
}

// ---------------- x = LayerNorm(x) in place ----------------
__global__ void ln_kernel(float* __restrict__ X, const float* __restrict__ g,
                          const float* __restrict__ be) {
  __shared__ float red[256];
  int row = blockIdx.x, tid = threadIdx.x;
  size_t base = (size_t)row * DM;
  float t0 = X[base + tid];
  float t1 = X[base + tid + 256];
  red[tid] = t0 + t1;
  __syncthreads();
  for (int s = 128; s >= 1; s >>= 1) { if (tid < s) red[tid] += red[tid + s]; __syncthreads(); }
  float mu = red[0] / 512.0f;
  __syncthreads();
  float d0 = t0 - mu, d1 = t1 - mu;
  red[tid] = d0 * d0 + d1 * d1;
  __syncthreads();
  for (int s = 128; s >= 1; s >>= 1) { if (tid < s) red[tid] += red[tid + s]; __syncthreads(); }
  float rstd = 1.0f / sqrtf(red[0] / 512.0f + 1e-5f);
  X[base + tid] = d0 * rstd * g[tid] + be[tid];
  X[base + tid + 256] = d1 * rstd * g[tid + 256] + be[tid + 256];
}

// ---------------- maxpool k=3 s=2 pad=1 along L ----------------
__global__ void pool_kernel(const float* __restrict__ Y, float* __restrict__ X, int L2) {
  int i = blockIdx.x * 256 + threadIdx.x;  // B*L2*DM
  int c = i % DM;
  int t = (i / DM) % L2;
  int b = i / (DM * L2);
  int L = L2 * 2;
  const float* yb = Y + (size_t)b * L * DM + c;
  float m = fmaxf(yb[(size_t)(2 * t) * DM], yb[(size_t)(2 * t + 1) * DM]);
  if (t > 0) m = fmaxf(m, yb[(size_t)(2 * t - 1) * DM]);
  X[i] = m;
}

// ---------------- column max, 2-stage ----------------
__global__ void colmax1_kernel(const float* __restrict__ X, float* __restrict__ P, int L) {
  int nlc = L >> 6;
  int bl = blockIdx.x;                     // B * nlc
  int b = bl / nlc, lc = bl % nlc;
  const float* xb = X + ((size_t)b * L + lc * 64) * DM;
  for (int c = threadIdx.x; c < DM; c += 256) {
    float m = -1e30f;
    for (int r = 0; r < 64; ++r) m = fmaxf(m, xb[(size_t)r * DM + c]);
    P[((size_t)b * nlc + lc) * DM + c] = m;
  }
}
__global__ void colmax2_kernel(const float* __restrict__ P, float* __restrict__ mc, int nlc) {
  int i = blockIdx.x * 256 + threadIdx.x;  // B*DM
  int b = i / DM, c = i % DM;
  float m = -1e30f;
  for (int lc = 0; lc < nlc; ++lc) m = fmaxf(m, P[((size_t)b * nlc + lc) * DM + c]);
  mc[i] = m;
}

// ---------------- final projection ----------------
__global__ void proj_kernel(const float* __restrict__ mc, const float* __restrict__ pw,
                            const float* __restrict__ pb, float* __restrict__ out) {
  __shared__ float red[256];
  int bo = blockIdx.x, b = bo / COUT, o = bo % COUT, tid = threadIdx.x;
  float s = mc[b * DM + tid] * pw[o * DM + tid] +
            mc[b * DM + tid + 256] * pw[o * DM + tid + 256];
  red[tid] = s;
  __syncthreads();
  for (int st = 128; st >= 1; st >>= 1) { if (tid < st) red[tid] += red[tid + st]; __syncthreads(); }
  if (tid == 0) out[bo] = red[0] + pb[o];
}

extern "C" void kernel_launch(void* const* d_in, const int* in_sizes, int n_in,
                              void* d_out, int out_size, void* d_ws, size_t ws_size,
                              hipStream_t stream) {
  (void)in_sizes; (void)n_in; (void)out_size;
  const float* xe   = (const float*)d_in[0];
  const float* tw   = (const float*)d_in[1];
  const float* Wq   = (const float*)d_in[2];
  const float* Wk   = (const float*)d_in[3];
  const float* Wv   = (const float*)d_in[4];
  const float* Wo   = (const float*)d_in[5];
  const float* bq   = (const float*)d_in[6];
  const float* bk   = (const float*)d_in[7];
  const float* bv   = (const float*)d_in[8];
  const float* bo   = (const float*)d_in[9];
  const float* W1   = (const float*)d_in[10];
  const float* b1   = (const float*)d_in[11];
  const float* W2   = (const float*)d_in[12];
  const float* b2   = (const float*)d_in[13];
  const float* ln1g = (const float*)d_in[14];
  const float* ln1b = (const float*)d_in[15];
  const float* ln2g = (const float*)d_in[16];
  const float* ln2b = (const float*)d_in[17];
  const float* dcw  = (const float*)d_in[18];
  const float* dcb  = (const float*)d_in[19];
  const float* bng  = (const float*)d_in[20];
  const float* bnb  = (const float*)d_in[21];
  const float* lnfg = (const float*)d_in[22];
  const float* lnfb = (const float*)d_in[23];
  const float* pw   = (const float*)d_in[24];
  const float* pb   = (const float*)d_in[25];
  float* out = (float*)d_out;

  float* Wf = (float*)d_ws;
  const size_t NB  = (size_t)B_ * LMAX * DM;   // 8,388,608
  const size_t NHB = (size_t)H_ * LMAX * DH;   // 1,048,576 per batch-elem QKV
  const size_t S_IDX = 81920, S_MV = 131072, S_TOP = 4096, S_VM = 4096,
               S_MC = 4096, S_P = 32768;
  const size_t SMALL = S_IDX + S_MV + S_TOP + S_VM + S_MC + S_P + 1024;

  // adaptive batch-group size g: Q/K/V buffers cost 3*g*NHB floats.
  int g = 8;
  while (g > 1 && (2 * NB + 3 * (size_t)g * NHB + SMALL) * 4 > ws_size) g >>= 1;

  float* X  = Wf;
  float* T  = X + NB;
  float* Q  = T + NB;
  float* K  = Q + (size_t)g * NHB;
  float* V  = K + (size_t)g * NHB;
  float* SM = V + (size_t)g * NHB;
  int*   IDX = (int*)SM;
  float* Mv  = SM + S_IDX;
  int*   TOP = (int*)(Mv + S_MV);
  float* VM  = Mv + S_MV + S_TOP;
  float* MC  = VM + S_VM;
  float* P   = MC + S_MC;
  float* Wt  = Q;   // 512*1536 = 786,432 floats; Q/K/V free during conv phase

  embed_kernel<<<B_ * LMAX * DM / 256, 256, 0, stream>>>(xe, tw, X);

  int L = LMAX;
  for (int i = 0; i < 3; ++i) {
    int U = (i == 0) ? 40 : 35;  // FACTOR * ceil(ln L)
    size_t wOff = (size_t)i * DM * DM;
    int ng = B_ / g;

    idx_kernel<<<(L * U + 255) / 256, 256, 0, stream>>>(IDX, L, U, i);

    for (int gb = 0; gb < ng; ++gb) {
      const float* Xg = X + (size_t)gb * g * L * DM;
      float* Tg = T + (size_t)gb * g * L * DM;
      dim3 gq(DM / 64, g * L / 128);
      tgemm<0, 1, 0, 0><<<gq, 256, 0, stream>>>(Xg, Wq + wOff, bq + i * DM, Q, L, DM);
      tgemm<0, 1, 0, 0><<<gq, 256, 0, stream>>>(Xg, Wk + wOff, bk + i * DM, K, L, DM);
      tgemm<0, 1, 0, 0><<<gq, 256, 0, stream>>>(Xg, Wv + wOff, bv + i * DM, V, L, DM);
      qkM_kernel<<<g * H_ * L / 4, 256, 0, stream>>>(Q, K, IDX, Mv, L, U);
      topk_kernel<<<g * H_, 256, 0, stream>>>(Mv, TOP, L, U);
      vmean_kernel<<<g * H_, 256, 0, stream>>>(V, VM, L);
      fill_kernel<<<(unsigned)((size_t)g * L * DM / 256), 256, 0, stream>>>(VM, Tg, L);
      attn_update_kernel<<<g * H_ * U, 256, 0, stream>>>(Q, K, V, TOP, Tg, L, U);
    }

    dim3 gf(DM / 64, B_ * L / 128);
    tgemm<0, 0, 1, 0><<<gf, 256, 0, stream>>>(T, Wo + wOff, bo + i * DM, X, L, DM);
    ln_kernel<<<B_ * L, 256, 0, stream>>>(X, ln1g + i * DM, ln1b + i * DM);
    tgemm<1, 0, 0, 0><<<gf, 256, 0, stream>>>(X, W1 + wOff, b1 + i * DM, T, L, DM);
    tgemm<0, 0, 1, 0><<<gf, 256, 0, stream>>>(T, W2 + wOff, b2 + i * DM, X, L, DM);
    ln_kernel<<<B_ * L, 256, 0, stream>>>(X, ln2g + i * DM, ln2b + i * DM);

    if (i < 2) {
      wt_kernel<<<DM * 1536 / 256, 256, 0, stream>>>(dcw + (size_t)i * DM * DM * 3, Wt);
      tgemm<0, 0, 0, 1><<<gf, 256, 0, stream>>>(X, Wt, nullptr, T, L, 1536);
      bnelu_kernel<<<B_ * L * DM / 256, 256, 0, stream>>>(T, dcb + i * DM, bng + i * DM,
                                                          bnb + i * DM);
      L >>= 1;
      pool_kernel<<<B_ * L * DM / 256, 256, 0, stream>>>(T, X, L);
    }
  }

  ln_kernel<<<B_ * L, 256, 0, stream>>>(X, lnfg, lnfb);
  colmax1_kernel<<<B_ * (L >> 6), 256, 0, stream>>>(X, P, L);
  colmax2_kernel<<<B_ * DM / 256, 256, 0, stream>>>(P, MC, L >> 6);
  proj_kernel<<<B_ * COUT, 256, 0, stream>>>(MC, pw, pb, out);
}

// Round 9
// 3710.106 us; speedup vs baseline: 6.9909x; 1.2869x over previous
//
#include <hip/hip_runtime.h>

#define B_ 8
#define H_ 8
#define DM 512
#define DH 64
#define LMAX 2048
#define COUT 2

// ---------------- JAX threefry2x32 ----------------
__device__ __forceinline__ void tf2x32(unsigned k0, unsigned k1, unsigned x0, unsigned x1,
                                       unsigned& o0, unsigned& o1) {
  unsigned ks2 = k0 ^ k1 ^ 0x1BD11BDAu;
  x0 += k0; x1 += k1;
#define RND(r) { x0 += x1; x1 = (x1 << r) | (x1 >> (32 - r)); x1 ^= x0; }
  RND(13) RND(15) RND(26) RND(6)  x0 += k1;  x1 += ks2 + 1u;
  RND(17) RND(29) RND(16) RND(24) x0 += ks2; x1 += k0 + 2u;
  RND(13) RND(15) RND(26) RND(6)  x0 += k0;  x1 += k1 + 3u;
  RND(17) RND(29) RND(16) RND(24) x0 += k1;  x1 += ks2 + 4u;
  RND(13) RND(15) RND(26) RND(6)  x0 += ks2; x1 += k0 + 5u;
#undef RND
  o0 = x0; o1 = x1;
}

// VERIFIED (R7, absmax 0.0): Variant B partitionable. DO NOT TOUCH.
__global__ void idx_kernel(int* __restrict__ idxArr, int L, int U, int layer) {
  int p = blockIdx.x * 256 + threadIdx.x;
  int half = L * U;
  if (p >= half) return;
  unsigned fk0, fk1, k20, k21, o0, o1;
  tf2x32(0u, 42u, 0u, (unsigned)layer, fk0, fk1);   // fold_in(key(42), layer)
  tf2x32(fk0, fk1, 0u, 1u, k20, k21);               // k2 = split(key)[1]
  tf2x32(k20, k21, 0u, (unsigned)p, o0, o1);        // bits[p], counter (0,p)
  idxArr[p] = (int)((o0 ^ o1) & (unsigned)(L - 1));
}

// ---------------- token embed + positional encoding ----------------
__global__ void embed_kernel(const float* __restrict__ xe, const float* __restrict__ tw,
                             float* __restrict__ X) {
  int i = blockIdx.x * 256 + threadIdx.x;          // B*LMAX*DM
  int c = i % DM;
  int l = (i / DM) % LMAX;
  int b = i / (DM * LMAX);
  int lm = (l + LMAX - 1) & (LMAX - 1);
  int lp = (l + 1) & (LMAX - 1);
  const float* xb = xe + b * LMAX;
  float tok = tw[c * 3 + 0] * xb[lm] + tw[c * 3 + 1] * xb[l] + tw[c * 3 + 2] * xb[lp];
  float freq = expf(-(float)(c & ~1) * (9.210340371976184f / 512.0f));
  float ang = (float)l * freq;
  float pe = (c & 1) ? cosf(ang) : sinf(ang);
  X[i] = tok + pe;
}

// ---------------- tiled GEMM: C[M,512] (+)= A @ W^T + bias ----------------
template <int ACT, int QKV, int ACC, int CONV>
__global__ __launch_bounds__(256) void tgemm(const float* __restrict__ A,
                                             const float* __restrict__ W,
                                             const float* __restrict__ bias,
                                             float* __restrict__ C, int L, int Ktot) {
  __shared__ float As[16][132];
  __shared__ float Bs[16][68];
  int tid = threadIdx.x;
  int n0 = blockIdx.x * 64, m0 = blockIdx.y * 128;
  int tx = tid & 15, ty = tid >> 4;
  float acc[8][4] = {};
  for (int k0 = 0; k0 < Ktot; k0 += 16) {
    int tap = 0, kcol = k0;
    if (CONV) { tap = k0 >> 9; kcol = k0 & 511; }
#pragma unroll
    for (int i = 0; i < 2; ++i) {
      int idx = tid + i * 256;
      int m = idx >> 2, kg = idx & 3;
      int row = m0 + m;
      const float* ap;
      if (CONV) {
        int b = row / L, l = row - b * L;
        int le = l + tap - 1;
        le = (le < 0) ? le + L : (le >= L ? le - L : le);
        ap = A + ((size_t)(b * L + le) * DM + kcol + kg * 4);
      } else {
        ap = A + ((size_t)row * DM + k0 + kg * 4);
      }
      float4 v = *(const float4*)ap;
      As[kg * 4 + 0][m] = v.x; As[kg * 4 + 1][m] = v.y;
      As[kg * 4 + 2][m] = v.z; As[kg * 4 + 3][m] = v.w;
    }
    {
      int n = tid >> 2, kg = tid & 3;
      float4 v = *(const float4*)(W + ((size_t)(n0 + n) * Ktot + k0 + kg * 4));
      Bs[kg * 4 + 0][n] = v.x; Bs[kg * 4 + 1][n] = v.y;
      Bs[kg * 4 + 2][n] = v.z; Bs[kg * 4 + 3][n] = v.w;
    }
    __syncthreads();
#pragma unroll
    for (int kk = 0; kk < 16; ++kk) {
      float a[8], b4[4];
#pragma unroll
      for (int i2 = 0; i2 < 8; ++i2) a[i2] = As[kk][ty * 8 + i2];
#pragma unroll
      for (int j = 0; j < 4; ++j) b4[j] = Bs[kk][tx * 4 + j];
#pragma unroll
      for (int i2 = 0; i2 < 8; ++i2)
#pragma unroll
        for (int j = 0; j < 4; ++j) acc[i2][j] += a[i2] * b4[j];
    }
    __syncthreads();
  }
#pragma unroll
  for (int i2 = 0; i2 < 8; ++i2) {
    int row = m0 + ty * 8 + i2;
#pragma unroll
    for (int j = 0; j < 4; ++j) {
      int col = n0 + tx * 4 + j;
      float v = acc[i2][j];
      if (!CONV) v += bias[col];
      if (ACT) v = 0.5f * v * (1.0f + erff(v * 0.70710678118654752f));
      if (QKV) {
        int b = row / L, l = row - b * L;
        int h = col >> 6, d = col & 63;
        C[(((size_t)b * H_ + h) * L + l) * DH + d] = v;
      } else if (ACC) {
        C[(size_t)row * DM + col] += v;
      } else {
        C[(size_t)row * DM + col] = v;
      }
    }
  }
}

// ---------------- conv weight transpose ----------------
__global__ void wt_kernel(const float* __restrict__ w, float* __restrict__ Wt) {
  int i = blockIdx.x * 256 + threadIdx.x;   // 512*1536
  int n = i / 1536, r = i - n * 1536, tap = r >> 9, k = r & 511;
  Wt[i] = w[((size_t)n * DM + k) * 3 + tap];
}

// ---------------- conv epilogue: BN + ELU ----------------
__global__ void bnelu_kernel(float* __restrict__ Y, const float* __restrict__ cb,
                             const float* __restrict__ g, const float* __restrict__ be) {
  int i = blockIdx.x * 256 + threadIdx.x;
  int c = i % DM;
  const float invs = 0.9999950000374997f;  // 1/sqrt(1+1e-5)
  float z = Y[i] + cb[c];
  z = z * invs * g[c] + be[c];
  Y[i] = z > 0.f ? z : expm1f(z);
}

// ---------------- sampled qk -> M = max_u - mean_u ----------------
__global__ void qkM_kernel(const float* __restrict__ Q, const float* __restrict__ Kd,
                           const int* __restrict__ idxArr, float* __restrict__ Mout,
                           int L, int U) {
  int lane = threadIdx.x & 63, wv = threadIdx.x >> 6;
  int row = blockIdx.x * 4 + wv;                    // over g*H*L
  int l = row % L, bh = row / L;
  float qd = Q[((size_t)bh * L + l) * DH + lane];
  float mx = -1e30f, sm = 0.f;
  for (int u = 0; u < U; ++u) {
    int ki = idxArr[l * U + u];
    float p = qd * Kd[((size_t)bh * L + ki) * DH + lane];
#pragma unroll
    for (int o = 32; o >= 1; o >>= 1) p += __shfl_xor(p, o, 64);
    mx = fmaxf(mx, p);
    sm += p;
  }
  if (lane == 0) Mout[row] = mx - sm / (float)U;
}

// ---------------- top-U per bh ----------------
__global__ void topk_kernel(const float* __restrict__ M, int* __restrict__ top, int L, int U) {
  __shared__ float vals[LMAX];
  __shared__ float rv[256];
  __shared__ int ri[256];
  int bh = blockIdx.x, tid = threadIdx.x;
  for (int j = tid; j < L; j += 256) vals[j] = M[(size_t)bh * L + j];
  __syncthreads();
  for (int u = 0; u < U; ++u) {
    float bv = -1e30f; int bi = L;
    for (int j = tid; j < L; j += 256) {
      float v = vals[j];
      if (v > bv) { bv = v; bi = j; }
    }
    rv[tid] = bv; ri[tid] = bi;
    __syncthreads();
    for (int s = 128; s >= 1; s >>= 1) {
      if (tid < s) {
        float ov = rv[tid + s]; int oi = ri[tid + s];
        if (ov > rv[tid] || (ov == rv[tid] && oi < ri[tid])) { rv[tid] = ov; ri[tid] = oi; }
      }
      __syncthreads();
    }
    if (tid == 0) { top[bh * U + u] = ri[0]; vals[ri[0]] = -1e30f; }
    __syncthreads();
  }
}

// ---------------- v mean over L per (bh,d) ----------------
__global__ void vmean_kernel(const float* __restrict__ V, float* __restrict__ VM, int L) {
  __shared__ float red[256];
  int bh = blockIdx.x, tid = threadIdx.x, d = tid & 63, sq = tid >> 6;
  float s = 0.f;
  for (int l = sq; l < L; l += 4) s += V[((size_t)bh * L + l) * DH + d];
  red[tid] = s;
  __syncthreads();
  if (sq == 0) VM[bh * DH + d] = (red[d] + red[d + 64] + red[d + 128] + red[d + 192]) / (float)L;
}

// ---------------- fill ctx (g,L,DM) with v-mean ----------------
__global__ void fill_kernel(const float* __restrict__ VM, float* __restrict__ O, int L) {
  size_t i = (size_t)blockIdx.x * 256 + threadIdx.x;  // g*L*DM
  int c = (int)(i % DM);
  int b = (int)(i / ((size_t)L * DM));
  O[i] = VM[b * DM + c];   // VM laid [g][H*DH=512]
}

// ---------------- flash-style attention for selected queries ----------------
// block = (bh, chunk of 8 queries). K staged transposed in LDS; online softmax.
__global__ __launch_bounds__(256) void attn_fused(const float* __restrict__ Q,
                                                  const float* __restrict__ Kd,
                                                  const float* __restrict__ V,
                                                  const int* __restrict__ top,
                                                  float* __restrict__ O, int L, int U) {
  __shared__ float Qs[8][64];
  __shared__ float Kt[64][65];   // transposed: Kt[d][j], conflict-free both phases
  __shared__ float Vs[64][68];
  __shared__ float ps[8][64];
  __shared__ int lst[8];
  int nch = (U + 7) >> 3;
  int bh = blockIdx.x / nch, ch = blockIdx.x - bh * nch;
  int u0g = ch * 8;
  int qn = U - u0g; if (qn > 8) qn = 8;
  int tid = threadIdx.x, lane = tid & 63, wv = tid >> 6;
  if (tid < qn) lst[tid] = top[bh * U + u0g + tid];
  __syncthreads();
  for (int idx = tid; idx < qn * 64; idx += 256) {
    int u = idx >> 6, d = idx & 63;
    Qs[u][d] = Q[((size_t)bh * L + lst[u]) * DH + d];
  }
  __syncthreads();
  int ua = wv, ub = wv + 4;
  bool hasA = ua < qn, hasB = ub < qn;
  float m0 = -1e30f, l0 = 0.f, o0 = 0.f;
  float m1 = -1e30f, l1 = 0.f, o1 = 0.f;
  const float* Kbase = Kd + (size_t)bh * L * DH;
  const float* Vbase = V + (size_t)bh * L * DH;
  for (int t0 = 0; t0 < L; t0 += 64) {
#pragma unroll
    for (int it = 0; it < 4; ++it) {
      int idx = tid + it * 256;            // 0..1023
      int j = idx >> 4, d4 = (idx & 15) * 4;
      float4 kv = *(const float4*)(Kbase + (size_t)(t0 + j) * DH + d4);
      Kt[d4 + 0][j] = kv.x; Kt[d4 + 1][j] = kv.y;
      Kt[d4 + 2][j] = kv.z; Kt[d4 + 3][j] = kv.w;
      *(float4*)&Vs[j][d4] = *(const float4*)(Vbase + (size_t)(t0 + j) * DH + d4);
    }
    __syncthreads();
    // scores: lane = key j
    float s0 = 0.f, s1 = 0.f;
#pragma unroll 16
    for (int d = 0; d < 64; ++d) {
      float kd = Kt[d][lane];
      s0 += kd * Qs[ua & 7][d];
      s1 += kd * Qs[ub & 7][d];
    }
    s0 *= 0.125f; s1 *= 0.125f;
    if (hasA) {
      float tm = s0;
#pragma unroll
      for (int o = 32; o >= 1; o >>= 1) tm = fmaxf(tm, __shfl_xor(tm, o, 64));
      float nm = fmaxf(m0, tm);
      float alpha = expf(m0 - nm);
      float p = expf(s0 - nm);
      float tsum = p;
#pragma unroll
      for (int o = 32; o >= 1; o >>= 1) tsum += __shfl_xor(tsum, o, 64);
      l0 = l0 * alpha + tsum;
      m0 = nm;
      ps[ua][lane] = p;
      o0 *= alpha;
    }
    if (hasB) {
      float tm = s1;
#pragma unroll
      for (int o = 32; o >= 1; o >>= 1) tm = fmaxf(tm, __shfl_xor(tm, o, 64));
      float nm = fmaxf(m1, tm);
      float alpha = expf(m1 - nm);
      float p = expf(s1 - nm);
      float tsum = p;
#pragma unroll
      for (int o = 32; o >= 1; o >>= 1) tsum += __shfl_xor(tsum, o, 64);
      l1 = l1 * alpha + tsum;
      m1 = nm;
      ps[ub][lane] = p;
      o1 *= alpha;
    }
    // PV: lane = d (same-wave LDS RAW; compiler inserts lgkmcnt waits)
    if (hasA) {
#pragma unroll 16
      for (int j = 0; j < 64; ++j) o0 += ps[ua][j] * Vs[j][lane];
    }
    if (hasB) {
#pragma unroll 16
      for (int j = 0; j < 64; ++j) o1 += ps[ub][j] * Vs[j][lane];
    }
    __syncthreads();
  }
  int b = bh / H_, h = bh - b * H_;
  if (hasA) O[((size_t)b * L + lst[ua]) * DM + h * DH + lane] = o0 / l0;
  if (hasB) O[((size_t)b * L + lst[ub]) * DM + h * DH + lane] = o1 / l1;
}

// ---------------- x = LayerNorm(x) in place ----------------
__global__ void ln_kernel(float* __restrict__ X, const float* __restrict__ g,
                          const float* __restrict__ be) {
  __shared__ float red[256];
  int row = blockIdx.x, tid = threadIdx.x;
  size_t base = (size_t)row * DM;
  float t0 = X[base + tid];
  float t1 = X[base + tid + 256];
  red[tid] = t0 + t1;
  __syncthreads();
  for (int s = 128; s >= 1; s >>= 1) { if (tid < s) red[tid] += red[tid + s]; __syncthreads(); }
  float mu = red[0] / 512.0f;
  __syncthreads();
  float d0 = t0 - mu, d1 = t1 - mu;
  red[tid] = d0 * d0 + d1 * d1;
  __syncthreads();
  for (int s = 128; s >= 1; s >>= 1) { if (tid < s) red[tid] += red[tid + s]; __syncthreads(); }
  float rstd = 1.0f / sqrtf(red[0] / 512.0f + 1e-5f);
  X[base + tid] = d0 * rstd * g[tid] + be[tid];
  X[base + tid + 256] = d1 * rstd * g[tid + 256] + be[tid + 256];
}

// ---------------- maxpool k=3 s=2 pad=1 along L ----------------
__global__ void pool_kernel(const float* __restrict__ Y, float* __restrict__ X, int L2) {
  int i = blockIdx.x * 256 + threadIdx.x;  // B*L2*DM
  int c = i % DM;
  int t = (i / DM) % L2;
  int b = i / (DM * L2);
  int L = L2 * 2;
  const float* yb = Y + (size_t)b * L * DM + c;
  float m = fmaxf(yb[(size_t)(2 * t) * DM], yb[(size_t)(2 * t + 1) * DM]);
  if (t > 0) m = fmaxf(m, yb[(size_t)(2 * t - 1) * DM]);
  X[i] = m;
}

// ---------------- column max, 2-stage ----------------
__global__ void colmax1_kernel(const float* __restrict__ X, float* __restrict__ P, int L) {
  int nlc = L >> 6;
  int bl = blockIdx.x;                     // B * nlc
  int b = bl / nlc, lc = bl % nlc;
  const float* xb = X + ((size_t)b * L + lc * 64) * DM;
  for (int c = threadIdx.x; c < DM; c += 256) {
    float m = -1e30f;
    for (int r = 0; r < 64; ++r) m = fmaxf(m, xb[(size_t)r * DM + c]);
    P[((size_t)b * nlc + lc) * DM + c] = m;
  }
}
__global__ void colmax2_kernel(const float* __restrict__ P, float* __restrict__ mc, int nlc) {
  int i = blockIdx.x * 256 + threadIdx.x;  // B*DM
  int b = i / DM, c = i % DM;
  float m = -1e30f;
  for (int lc = 0; lc < nlc; ++lc) m = fmaxf(m, P[((size_t)b * nlc + lc) * DM + c]);
  mc[i] = m;
}

// ---------------- final projection ----------------
__global__ void proj_kernel(const float* __restrict__ mc, const float* __restrict__ pw,
                            const float* __restrict__ pb, float* __restrict__ out) {
  __shared__ float red[256];
  int bo = blockIdx.x, b = bo / COUT, o = bo % COUT, tid = threadIdx.x;
  float s = mc[b * DM + tid] * pw[o * DM + tid] +
            mc[b * DM + tid + 256] * pw[o * DM + tid + 256];
  red[tid] = s;
  __syncthreads();
  for (int st = 128; st >= 1; st >>= 1) { if (tid < st) red[tid] += red[tid + st]; __syncthreads(); }
  if (tid == 0) out[bo] = red[0] + pb[o];
}

extern "C" void kernel_launch(void* const* d_in, const int* in_sizes, int n_in,
                              void* d_out, int out_size, void* d_ws, size_t ws_size,
                              hipStream_t stream) {
  (void)in_sizes; (void)n_in; (void)out_size;
  const float* xe   = (const float*)d_in[0];
  const float* tw   = (const float*)d_in[1];
  const float* Wq   = (const float*)d_in[2];
  const float* Wk   = (const float*)d_in[3];
  const float* Wv   = (const float*)d_in[4];
  const float* Wo   = (const float*)d_in[5];
  const float* bq   = (const float*)d_in[6];
  const float* bk   = (const float*)d_in[7];
  const float* bv   = (const float*)d_in[8];
  const float* bo   = (const float*)d_in[9];
  const float* W1   = (const float*)d_in[10];
  const float* b1   = (const float*)d_in[11];
  const float* W2   = (const float*)d_in[12];
  const float* b2   = (const float*)d_in[13];
  const float* ln1g = (const float*)d_in[14];
  const float* ln1b = (const float*)d_in[15];
  const float* ln2g = (const float*)d_in[16];
  const float* ln2b = (const float*)d_in[17];
  const float* dcw  = (const float*)d_in[18];
  const float* dcb  = (const float*)d_in[19];
  const float* bng  = (const float*)d_in[20];
  const float* bnb  = (const float*)d_in[21];
  const float* lnfg = (const float*)d_in[22];
  const float* lnfb = (const float*)d_in[23];
  const float* pw   = (const float*)d_in[24];
  const float* pb   = (const float*)d_in[25];
  float* out = (float*)d_out;

  float* Wf = (float*)d_ws;
  const size_t NB  = (size_t)B_ * LMAX * DM;   // 8,388,608
  const size_t NHB = (size_t)H_ * LMAX * DH;   // 1,048,576 per batch-elem QKV
  const size_t S_IDX = 81920, S_MV = 131072, S_TOP = 4096, S_VM = 4096,
               S_MC = 4096, S_P = 32768;
  const size_t SMALL = S_IDX + S_MV + S_TOP + S_VM + S_MC + S_P + 1024;

  int g = 8;
  while (g > 1 && (2 * NB + 3 * (size_t)g * NHB + SMALL) * 4 > ws_size) g >>= 1;

  float* X  = Wf;
  float* T  = X + NB;
  float* Q  = T + NB;
  float* K  = Q + (size_t)g * NHB;
  float* V  = K + (size_t)g * NHB;
  float* SM = V + (size_t)g * NHB;
  int*   IDX = (int*)SM;
  float* Mv  = SM + S_IDX;
  int*   TOP = (int*)(Mv + S_MV);
  float* VM  = Mv + S_MV + S_TOP;
  float* MC  = VM + S_VM;
  float* P   = MC + S_MC;
  float* Wt  = Q;   // Q/K/V free during conv phase

  embed_kernel<<<B_ * LMAX * DM / 256, 256, 0, stream>>>(xe, tw, X);

  int L = LMAX;
  for (int i = 0; i < 3; ++i) {
    int U = (i == 0) ? 40 : 35;  // FACTOR * ceil(ln L)
    size_t wOff = (size_t)i * DM * DM;
    int ng = B_ / g;
    int nch = (U + 7) >> 3;

    idx_kernel<<<(L * U + 255) / 256, 256, 0, stream>>>(IDX, L, U, i);

    for (int gb = 0; gb < ng; ++gb) {
      const float* Xg = X + (size_t)gb * g * L * DM;
      float* Tg = T + (size_t)gb * g * L * DM;
      dim3 gq(DM / 64, g * L / 128);
      tgemm<0, 1, 0, 0><<<gq, 256, 0, stream>>>(Xg, Wq + wOff, bq + i * DM, Q, L, DM);
      tgemm<0, 1, 0, 0><<<gq, 256, 0, stream>>>(Xg, Wk + wOff, bk + i * DM, K, L, DM);
      tgemm<0, 1, 0, 0><<<gq, 256, 0, stream>>>(Xg, Wv + wOff, bv + i * DM, V, L, DM);
      qkM_kernel<<<g * H_ * L / 4, 256, 0, stream>>>(Q, K, IDX, Mv, L, U);
      topk_kernel<<<g * H_, 256, 0, stream>>>(Mv, TOP, L, U);
      vmean_kernel<<<g * H_, 256, 0, stream>>>(V, VM, L);
      fill_kernel<<<(unsigned)((size_t)g * L * DM / 256), 256, 0, stream>>>(VM, Tg, L);
      attn_fused<<<g * H_ * nch, 256, 0, stream>>>(Q, K, V, TOP, Tg, L, U);
    }

    dim3 gf(DM / 64, B_ * L / 128);
    tgemm<0, 0, 1, 0><<<gf, 256, 0, stream>>>(T, Wo + wOff, bo + i * DM, X, L, DM);
    ln_kernel<<<B_ * L, 256, 0, stream>>>(X, ln1g + i * DM, ln1b + i * DM);
    tgemm<1, 0, 0, 0><<<gf, 256, 0, stream>>>(X, W1 + wOff, b1 + i * DM, T, L, DM);
    tgemm<0, 0, 1, 0><<<gf, 256, 0, stream>>>(T, W2 + wOff, b2 + i * DM, X, L, DM);
    ln_kernel<<<B_ * L, 256, 0, stream>>>(X, ln2g + i * DM, ln2b + i * DM);

    if (i < 2) {
      wt_kernel<<<DM * 1536 / 256, 256, 0, stream>>>(dcw + (size_t)i * DM * DM * 3, Wt);
      tgemm<0, 0, 0, 1><<<gf, 256, 0, stream>>>(X, Wt, nullptr, T, L, 1536);
      bnelu_kernel<<<B_ * L * DM / 256, 256, 0, stream>>>(T, dcb + i * DM, bng + i * DM,
                                                          bnb + i * DM);
      L >>= 1;
      pool_kernel<<<B_ * L * DM / 256, 256, 0, stream>>>(T, X, L);
    }
  }

  ln_kernel<<<B_ * L, 256, 0, stream>>>(X, lnfg, lnfb);
  colmax1_kernel<<<B_ * (L >> 6), 256, 0, stream>>>(X, P, L);
  colmax2_kernel<<<B_ * DM / 256, 256, 0, stream>>>(P, MC, L >> 6);
  proj_kernel<<<B_ * COUT, 256, 0, stream>>>(MC, pw, pb, out);
}

// Round 10
// 3568.031 us; speedup vs baseline: 7.2692x; 1.0398x over previous
//
#include <hip/hip_runtime.h>

#define B_ 8
#define H_ 8
#define DM 512
#define DH 64
#define LMAX 2048
#define COUT 2

// ---------------- JAX threefry2x32 ----------------
__device__ __forceinline__ void tf2x32(unsigned k0, unsigned k1, unsigned x0, unsigned x1,
                                       unsigned& o0, unsigned& o1) {
  unsigned ks2 = k0 ^ k1 ^ 0x1BD11BDAu;
  x0 += k0; x1 += k1;
#define RND(r) { x0 += x1; x1 = (x1 << r) | (x1 >> (32 - r)); x1 ^= x0; }
  RND(13) RND(15) RND(26) RND(6)  x0 += k1;  x1 += ks2 + 1u;
  RND(17) RND(29) RND(16) RND(24) x0 += ks2; x1 += k0 + 2u;
  RND(13) RND(15) RND(26) RND(6)  x0 += k0;  x1 += k1 + 3u;
  RND(17) RND(29) RND(16) RND(24) x0 += k1;  x1 += ks2 + 4u;
  RND(13) RND(15) RND(26) RND(6)  x0 += ks2; x1 += k0 + 5u;
#undef RND
  o0 = x0; o1 = x1;
}

// VERIFIED (R7, absmax 0.0): Variant B partitionable. DO NOT TOUCH.
__global__ void idx_kernel(int* __restrict__ idxArr, int L, int U, int layer) {
  int p = blockIdx.x * 256 + threadIdx.x;
  int half = L * U;
  if (p >= half) return;
  unsigned fk0, fk1, k20, k21, o0, o1;
  tf2x32(0u, 42u, 0u, (unsigned)layer, fk0, fk1);   // fold_in(key(42), layer)
  tf2x32(fk0, fk1, 0u, 1u, k20, k21);               // k2 = split(key)[1]
  tf2x32(k20, k21, 0u, (unsigned)p, o0, o1);        // bits[p], counter (0,p)
  idxArr[p] = (int)((o0 ^ o1) & (unsigned)(L - 1));
}

// ---------------- token embed + positional encoding ----------------
__global__ void embed_kernel(const float* __restrict__ xe, const float* __restrict__ tw,
                             float* __restrict__ X) {
  int i = blockIdx.x * 256 + threadIdx.x;          // B*LMAX*DM
  int c = i % DM;
  int l = (i / DM) % LMAX;
  int b = i / (DM * LMAX);
  int lm = (l + LMAX - 1) & (LMAX - 1);
  int lp = (l + 1) & (LMAX - 1);
  const float* xb = xe + b * LMAX;
  float tok = tw[c * 3 + 0] * xb[lm] + tw[c * 3 + 1] * xb[l] + tw[c * 3 + 2] * xb[lp];
  float freq = expf(-(float)(c & ~1) * (9.210340371976184f / 512.0f));
  float ang = (float)l * freq;
  float pe = (c & 1) ? cosf(ang) : sinf(ang);
  X[i] = tok + pe;
}

// ---------------- tiled GEMM: C[M,512] (+)= A @ W^T + bias ----------------
template <int ACT, int QKV, int ACC, int CONV>
__global__ __launch_bounds__(256) void tgemm(const float* __restrict__ A,
                                             const float* __restrict__ W,
                                             const float* __restrict__ bias,
                                             float* __restrict__ C, int L, int Ktot) {
  __shared__ float As[16][132];
  __shared__ float Bs[16][68];
  int tid = threadIdx.x;
  int n0 = blockIdx.x * 64, m0 = blockIdx.y * 128;
  int tx = tid & 15, ty = tid >> 4;
  float acc[8][4] = {};
  for (int k0 = 0; k0 < Ktot; k0 += 16) {
    int tap = 0, kcol = k0;
    if (CONV) { tap = k0 >> 9; kcol = k0 & 511; }
#pragma unroll
    for (int i = 0; i < 2; ++i) {
      int idx = tid + i * 256;
      int m = idx >> 2, kg = idx & 3;
      int row = m0 + m;
      const float* ap;
      if (CONV) {
        int b = row / L, l = row - b * L;
        int le = l + tap - 1;
        le = (le < 0) ? le + L : (le >= L ? le - L : le);
        ap = A + ((size_t)(b * L + le) * DM + kcol + kg * 4);
      } else {
        ap = A + ((size_t)row * DM + k0 + kg * 4);
      }
      float4 v = *(const float4*)ap;
      As[kg * 4 + 0][m] = v.x; As[kg * 4 + 1][m] = v.y;
      As[kg * 4 + 2][m] = v.z; As[kg * 4 + 3][m] = v.w;
    }
    {
      int n = tid >> 2, kg = tid & 3;
      float4 v = *(const float4*)(W + ((size_t)(n0 + n) * Ktot + k0 + kg * 4));
      Bs[kg * 4 + 0][n] = v.x; Bs[kg * 4 + 1][n] = v.y;
      Bs[kg * 4 + 2][n] = v.z; Bs[kg * 4 + 3][n] = v.w;
    }
    __syncthreads();
#pragma unroll
    for (int kk = 0; kk < 16; ++kk) {
      float a[8], b4[4];
#pragma unroll
      for (int i2 = 0; i2 < 8; ++i2) a[i2] = As[kk][ty * 8 + i2];
#pragma unroll
      for (int j = 0; j < 4; ++j) b4[j] = Bs[kk][tx * 4 + j];
#pragma unroll
      for (int i2 = 0; i2 < 8; ++i2)
#pragma unroll
        for (int j = 0; j < 4; ++j) acc[i2][j] += a[i2] * b4[j];
    }
    __syncthreads();
  }
#pragma unroll
  for (int i2 = 0; i2 < 8; ++i2) {
    int row = m0 + ty * 8 + i2;
#pragma unroll
    for (int j = 0; j < 4; ++j) {
      int col = n0 + tx * 4 + j;
      float v = acc[i2][j];
      if (!CONV) v += bias[col];
      if (ACT) v = 0.5f * v * (1.0f + erff(v * 0.70710678118654752f));
      if (QKV) {
        int b = row / L, l = row - b * L;
        int h = col >> 6, d = col & 63;
        C[(((size_t)b * H_ + h) * L + l) * DH + d] = v;
      } else if (ACC) {
        C[(size_t)row * DM + col] += v;
      } else {
        C[(size_t)row * DM + col] = v;
      }
    }
  }
}

// ---------------- conv weight transpose ----------------
__global__ void wt_kernel(const float* __restrict__ w, float* __restrict__ Wt) {
  int i = blockIdx.x * 256 + threadIdx.x;   // 512*1536
  int n = i / 1536, r = i - n * 1536, tap = r >> 9, k = r & 511;
  Wt[i] = w[((size_t)n * DM + k) * 3 + tap];
}

// ---------------- conv epilogue: BN + ELU ----------------
__global__ void bnelu_kernel(float* __restrict__ Y, const float* __restrict__ cb,
                             const float* __restrict__ g, const float* __restrict__ be) {
  int i = blockIdx.x * 256 + threadIdx.x;
  int c = i % DM;
  const float invs = 0.9999950000374997f;  // 1/sqrt(1+1e-5)
  float z = Y[i] + cb[c];
  z = z * invs * g[c] + be[c];
  Y[i] = z > 0.f ? z : expm1f(z);
}

// ---------------- sampled qk -> M = max_u - mean_u; 5-way ILP unroll ----------------
__global__ void qkM_kernel(const float* __restrict__ Q, const float* __restrict__ Kd,
                           const int* __restrict__ idxArr, float* __restrict__ Mout,
                           int L, int U) {
  int lane = threadIdx.x & 63, wv = threadIdx.x >> 6;
  int row = blockIdx.x * 4 + wv;                    // over g*H*L
  int l = row % L, bh = row / L;
  float qd = Q[((size_t)bh * L + l) * DH + lane];
  const float* Kb = Kd + (size_t)bh * L * DH + lane;
  const int* ip = idxArr + l * U;
  float mx = -1e30f, sm = 0.f;
  for (int u = 0; u < U; u += 5) {              // U in {40,35}: both %5==0
    int k0 = ip[u], k1 = ip[u + 1], k2 = ip[u + 2], k3 = ip[u + 3], k4 = ip[u + 4];
    float p0 = qd * Kb[(size_t)k0 * DH];
    float p1 = qd * Kb[(size_t)k1 * DH];
    float p2 = qd * Kb[(size_t)k2 * DH];
    float p3 = qd * Kb[(size_t)k3 * DH];
    float p4 = qd * Kb[(size_t)k4 * DH];
#pragma unroll
    for (int o = 32; o >= 1; o >>= 1) {         // 5 independent butterfly chains
      p0 += __shfl_xor(p0, o, 64);
      p1 += __shfl_xor(p1, o, 64);
      p2 += __shfl_xor(p2, o, 64);
      p3 += __shfl_xor(p3, o, 64);
      p4 += __shfl_xor(p4, o, 64);
    }
    mx = fmaxf(mx, fmaxf(fmaxf(p0, p1), fmaxf(fmaxf(p2, p3), p4)));
    sm += p0 + p1 + p2 + p3 + p4;
  }
  if (lane == 0) Mout[row] = mx - sm / (float)U;
}

// ---------------- top-U per bh ----------------
__global__ void topk_kernel(const float* __restrict__ M, int* __restrict__ top, int L, int U) {
  __shared__ float vals[LMAX];
  __shared__ float rv[256];
  __shared__ int ri[256];
  int bh = blockIdx.x, tid = threadIdx.x;
  for (int j = tid; j < L; j += 256) vals[j] = M[(size_t)bh * L + j];
  __syncthreads();
  for (int u = 0; u < U; ++u) {
    float bv = -1e30f; int bi = L;
    for (int j = tid; j < L; j += 256) {
      float v = vals[j];
      if (v > bv) { bv = v; bi = j; }
    }
    rv[tid] = bv; ri[tid] = bi;
    __syncthreads();
    for (int s = 128; s >= 1; s >>= 1) {
      if (tid < s) {
        float ov = rv[tid + s]; int oi = ri[tid + s];
        if (ov > rv[tid] || (ov == rv[tid] && oi < ri[tid])) { rv[tid] = ov; ri[tid] = oi; }
      }
      __syncthreads();
    }
    if (tid == 0) { top[bh * U + u] = ri[0]; vals[ri[0]] = -1e30f; }
    __syncthreads();
  }
}

// ---------------- v mean over L per (bh,d) ----------------
__global__ void vmean_kernel(const float* __restrict__ V, float* __restrict__ VM, int L) {
  __shared__ float red[256];
  int bh = blockIdx.x, tid = threadIdx.x, d = tid & 63, sq = tid >> 6;
  float s = 0.f;
  for (int l = sq; l < L; l += 4) s += V[((size_t)bh * L + l) * DH + d];
  red[tid] = s;
  __syncthreads();
  if (sq == 0) VM[bh * DH + d] = (red[d] + red[d + 64] + red[d + 128] + red[d + 192]) / (float)L;
}

// ---------------- fill ctx (g,L,DM) with v-mean ----------------
__global__ void fill_kernel(const float* __restrict__ VM, float* __restrict__ O, int L) {
  size_t i = (size_t)blockIdx.x * 256 + threadIdx.x;  // g*L*DM
  int c = (int)(i % DM);
  int b = (int)(i / ((size_t)L * DM));
  O[i] = VM[b * DM + c];   // VM laid [g][H*DH=512]
}

// ---------------- flash-style attention for selected queries ----------------
__global__ __launch_bounds__(256) void attn_fused(const float* __restrict__ Q,
                                                  const float* __restrict__ Kd,
                                                  const float* __restrict__ V,
                                                  const int* __restrict__ top,
                                                  float* __restrict__ O, int L, int U) {
  __shared__ float Qs[8][64];
  __shared__ float Kt[64][65];   // transposed: Kt[d][j]
  __shared__ float Vs[64][68];
  __shared__ float ps[8][64];
  __shared__ int lst[8];
  int nch = (U + 7) >> 3;
  int bh = blockIdx.x / nch, ch = blockIdx.x - bh * nch;
  int u0g = ch * 8;
  int qn = U - u0g; if (qn > 8) qn = 8;
  int tid = threadIdx.x, lane = tid & 63, wv = tid >> 6;
  if (tid < qn) lst[tid] = top[bh * U + u0g + tid];
  __syncthreads();
  for (int idx = tid; idx < qn * 64; idx += 256) {
    int u = idx >> 6, d = idx & 63;
    Qs[u][d] = Q[((size_t)bh * L + lst[u]) * DH + d];
  }
  __syncthreads();
  int ua = wv, ub = wv + 4;
  bool hasA = ua < qn, hasB = ub < qn;
  float m0 = -1e30f, l0 = 0.f, o0 = 0.f;
  float m1 = -1e30f, l1 = 0.f, o1 = 0.f;
  const float* Kbase = Kd + (size_t)bh * L * DH;
  const float* Vbase = V + (size_t)bh * L * DH;
  for (int t0 = 0; t0 < L; t0 += 64) {
#pragma unroll
    for (int it = 0; it < 4; ++it) {
      int idx = tid + it * 256;            // 0..1023
      int j = idx >> 4, d4 = (idx & 15) * 4;
      float4 kv = *(const float4*)(Kbase + (size_t)(t0 + j) * DH + d4);
      Kt[d4 + 0][j] = kv.x; Kt[d4 + 1][j] = kv.y;
      Kt[d4 + 2][j] = kv.z; Kt[d4 + 3][j] = kv.w;
      *(float4*)&Vs[j][d4] = *(const float4*)(Vbase + (size_t)(t0 + j) * DH + d4);
    }
    __syncthreads();
    float s0 = 0.f, s1 = 0.f;
#pragma unroll 16
    for (int d = 0; d < 64; ++d) {
      float kd = Kt[d][lane];
      s0 += kd * Qs[ua & 7][d];
      s1 += kd * Qs[ub & 7][d];
    }
    s0 *= 0.125f; s1 *= 0.125f;
    if (hasA) {
      float tm = s0;
#pragma unroll
      for (int o = 32; o >= 1; o >>= 1) tm = fmaxf(tm, __shfl_xor(tm, o, 64));
      float nm = fmaxf(m0, tm);
      float alpha = expf(m0 - nm);
      float p = expf(s0 - nm);
      float tsum = p;
#pragma unroll
      for (int o = 32; o >= 1; o >>= 1) tsum += __shfl_xor(tsum, o, 64);
      l0 = l0 * alpha + tsum;
      m0 = nm;
      ps[ua][lane] = p;
      o0 *= alpha;
    }
    if (hasB) {
      float tm = s1;
#pragma unroll
      for (int o = 32; o >= 1; o >>= 1) tm = fmaxf(tm, __shfl_xor(tm, o, 64));
      float nm = fmaxf(m1, tm);
      float alpha = expf(m1 - nm);
      float p = expf(s1 - nm);
      float tsum = p;
#pragma unroll
      for (int o = 32; o >= 1; o >>= 1) tsum += __shfl_xor(tsum, o, 64);
      l1 = l1 * alpha + tsum;
      m1 = nm;
      ps[ub][lane] = p;
      o1 *= alpha;
    }
    if (hasA) {
#pragma unroll 16
      for (int j = 0; j < 64; ++j) o0 += ps[ua][j] * Vs[j][lane];
    }
    if (hasB) {
#pragma unroll 16
      for (int j = 0; j < 64; ++j) o1 += ps[ub][j] * Vs[j][lane];
    }
    __syncthreads();
  }
  int b = bh / H_, h = bh - b * H_;
  if (hasA) O[((size_t)b * L + lst[ua]) * DM + h * DH + lane] = o0 / l0;
  if (hasB) O[((size_t)b * L + lst[ub]) * DM + h * DH + lane] = o1 / l1;
}

// ---------------- x = LayerNorm(x) in place ----------------
__global__ void ln_kernel(float* __restrict__ X, const float* __restrict__ g,
                          const float* __restrict__ be) {
  __shared__ float red[256];
  int row = blockIdx.x, tid = threadIdx.x;
  size_t base = (size_t)row * DM;
  float t0 = X[base + tid];
  float t1 = X[base + tid + 256];
  red[tid] = t0 + t1;
  __syncthreads();
  for (int s = 128; s >= 1; s >>= 1) { if (tid < s) red[tid] += red[tid + s]; __syncthreads(); }
  float mu = red[0] / 512.0f;
  __syncthreads();
  float d0 = t0 - mu, d1 = t1 - mu;
  red[tid] = d0 * d0 + d1 * d1;
  __syncthreads();
  for (int s = 128; s >= 1; s >>= 1) { if (tid < s) red[tid] += red[tid + s]; __syncthreads(); }
  float rstd = 1.0f / sqrtf(red[0] / 512.0f + 1e-5f);
  X[base + tid] = d0 * rstd * g[tid] + be[tid];
  X[base + tid + 256] = d1 * rstd * g[tid + 256] + be[tid + 256];
}

// ---------------- maxpool k=3 s=2 pad=1 along L ----------------
__global__ void pool_kernel(const float* __restrict__ Y, float* __restrict__ X, int L2) {
  int i = blockIdx.x * 256 + threadIdx.x;  // B*L2*DM
  int c = i % DM;
  int t = (i / DM) % L2;
  int b = i / (DM * L2);
  int L = L2 * 2;
  const float* yb = Y + (size_t)b * L * DM + c;
  float m = fmaxf(yb[(size_t)(2 * t) * DM], yb[(size_t)(2 * t + 1) * DM]);
  if (t > 0) m = fmaxf(m, yb[(size_t)(2 * t - 1) * DM]);
  X[i] = m;
}

// ---------------- column max, 2-stage ----------------
__global__ void colmax1_kernel(const float* __restrict__ X, float* __restrict__ P, int L) {
  int nlc = L >> 6;
  int bl = blockIdx.x;                     // B * nlc
  int b = bl / nlc, lc = bl % nlc;
  const float* xb = X + ((size_t)b * L + lc * 64) * DM;
  for (int c = threadIdx.x; c < DM; c += 256) {
    float m = -1e30f;
    for (int r = 0; r < 64; ++r) m = fmaxf(m, xb[(size_t)r * DM + c]);
    P[((size_t)b * nlc + lc) * DM + c] = m;
  }
}
__global__ void colmax2_kernel(const float* __restrict__ P, float* __restrict__ mc, int nlc) {
  int i = blockIdx.x * 256 + threadIdx.x;  // B*DM
  int b = i / DM, c = i % DM;
  float m = -1e30f;
  for (int lc = 0; lc < nlc; ++lc) m = fmaxf(m, P[((size_t)b * nlc + lc) * DM + c]);
  mc[i] = m;
}

// ---------------- final projection ----------------
__global__ void proj_kernel(const float* __restrict__ mc, const float* __restrict__ pw,
                            const float* __restrict__ pb, float* __restrict__ out) {
  __shared__ float red[256];
  int bo = blockIdx.x, b = bo / COUT, o = bo % COUT, tid = threadIdx.x;
  float s = mc[b * DM + tid] * pw[o * DM + tid] +
            mc[b * DM + tid + 256] * pw[o * DM + tid + 256];
  red[tid] = s;
  __syncthreads();
  for (int st = 128; st >= 1; st >>= 1) { if (tid < st) red[tid] += red[tid + st]; __syncthreads(); }
  if (tid == 0) out[bo] = red[0] + pb[o];
}

extern "C" void kernel_launch(void* const* d_in, const int* in_sizes, int n_in,
                              void* d_out, int out_size, void* d_ws, size_t ws_size,
                              hipStream_t stream) {
  (void)in_sizes; (void)n_in; (void)out_size;
  const float* xe   = (const float*)d_in[0];
  const float* tw   = (const float*)d_in[1];
  const float* Wq   = (const float*)d_in[2];
  const float* Wk   = (const float*)d_in[3];
  const float* Wv   = (const float*)d_in[4];
  const float* Wo   = (const float*)d_in[5];
  const float* bq   = (const float*)d_in[6];
  const float* bk   = (const float*)d_in[7];
  const float* bv   = (const float*)d_in[8];
  const float* bo   = (const float*)d_in[9];
  const float* W1   = (const float*)d_in[10];
  const float* b1   = (const float*)d_in[11];
  const float* W2   = (const float*)d_in[12];
  const float* b2   = (const float*)d_in[13];
  const float* ln1g = (const float*)d_in[14];
  const float* ln1b = (const float*)d_in[15];
  const float* ln2g = (const float*)d_in[16];
  const float* ln2b = (const float*)d_in[17];
  const float* dcw  = (const float*)d_in[18];
  const float* dcb  = (const float*)d_in[19];
  const float* bng  = (const float*)d_in[20];
  const float* bnb  = (const float*)d_in[21];
  const float* lnfg = (const float*)d_in[22];
  const float* lnfb = (const float*)d_in[23];
  const float* pw   = (const float*)d_in[24];
  const float* pb   = (const float*)d_in[25];
  float* out = (float*)d_out;

  float* Wf = (float*)d_ws;
  const size_t NB  = (size_t)B_ * LMAX * DM;   // 8,388,608
  const size_t NHB = (size_t)H_ * LMAX * DH;   // 1,048,576 per batch-elem QKV
  const size_t S_IDX = 81920, S_MV = 131072, S_TOP = 4096, S_VM = 4096,
               S_MC = 4096, S_P = 32768;
  const size_t SMALL = S_IDX + S_MV + S_TOP + S_VM + S_MC + S_P + 1024;

  int g = 8;
  while (g > 1 && (2 * NB + 3 * (size_t)g * NHB + SMALL) * 4 > ws_size) g >>= 1;

  float* X  = Wf;
  float* T  = X + NB;
  float* Q  = T + NB;
  float* K  = Q + (size_t)g * NHB;
  float* V  = K + (size_t)g * NHB;
  float* SM = V + (size_t)g * NHB;
  int*   IDX = (int*)SM;
  float* Mv  = SM + S_IDX;
  int*   TOP = (int*)(Mv + S_MV);
  float* VM  = Mv + S_MV + S_TOP;
  float* MC  = VM + S_VM;
  float* P   = MC + S_MC;
  float* Wt  = Q;   // Q/K/V free during conv phase

  embed_kernel<<<B_ * LMAX * DM / 256, 256, 0, stream>>>(xe, tw, X);

  int L = LMAX;
  for (int i = 0; i < 3; ++i) {
    int U = (i == 0) ? 40 : 35;  // FACTOR * ceil(ln L)
    size_t wOff = (size_t)i * DM * DM;
    int ng = B_ / g;
    int nch = (U + 7) >> 3;

    idx_kernel<<<(L * U + 255) / 256, 256, 0, stream>>>(IDX, L, U, i);

    for (int gb = 0; gb < ng; ++gb) {
      const float* Xg = X + (size_t)gb * g * L * DM;
      float* Tg = T + (size_t)gb * g * L * DM;
      dim3 gq(DM / 64, g * L / 128);
      tgemm<0, 1, 0, 0><<<gq, 256, 0, stream>>>(Xg, Wq + wOff, bq + i * DM, Q, L, DM);
      tgemm<0, 1, 0, 0><<<gq, 256, 0, stream>>>(Xg, Wk + wOff, bk + i * DM, K, L, DM);
      tgemm<0, 1, 0, 0><<<gq, 256, 0, stream>>>(Xg, Wv + wOff, bv + i * DM, V, L, DM);
      qkM_kernel<<<g * H_ * L / 4, 256, 0, stream>>>(Q, K, IDX, Mv, L, U);
      topk_kernel<<<g * H_, 256, 0, stream>>>(Mv, TOP, L, U);
      vmean_kernel<<<g * H_, 256, 0, stream>>>(V, VM, L);
      fill_kernel<<<(unsigned)((size_t)g * L * DM / 256), 256, 0, stream>>>(VM, Tg, L);
      attn_fused<<<g * H_ * nch, 256, 0, stream>>>(Q, K, V, TOP, Tg, L, U);
    }

    dim3 gf(DM / 64, B_ * L / 128);
    tgemm<0, 0, 1, 0><<<gf, 256, 0, stream>>>(T, Wo + wOff, bo + i * DM, X, L, DM);
    ln_kernel<<<B_ * L, 256, 0, stream>>>(X, ln1g + i * DM, ln1b + i * DM);
    tgemm<1, 0, 0, 0><<<gf, 256, 0, stream>>>(X, W1 + wOff, b1 + i * DM, T, L, DM);
    tgemm<0, 0, 1, 0><<<gf, 256, 0, stream>>>(T, W2 + wOff, b2 + i * DM, X, L, DM);
    ln_kernel<<<B_ * L, 256, 0, stream>>>(X, ln2g + i * DM, ln2b + i * DM);

    if (i < 2) {
      wt_kernel<<<DM * 1536 / 256, 256, 0, stream>>>(dcw + (size_t)i * DM * DM * 3, Wt);
      tgemm<0, 0, 0, 1><<<gf, 256, 0, stream>>>(X, Wt, nullptr, T, L, 1536);
      bnelu_kernel<<<B_ * L * DM / 256, 256, 0, stream>>>(T, dcb + i * DM, bng + i * DM,
                                                          bnb + i * DM);
      L >>= 1;
      pool_kernel<<<B_ * L * DM / 256, 256, 0, stream>>>(T, X, L);
    }
  }

  ln_kernel<<<B_ * L, 256, 0, stream>>>(X, lnfg, lnfb);
  colmax1_kernel<<<B_ * (L >> 6), 256, 0, stream>>>(X, P, L);
  colmax2_kernel<<<B_ * DM / 256, 256, 0, stream>>>(P, MC, L >> 6);
  proj_kernel<<<B_ * COUT, 256, 0, stream>>>(MC, pw, pb, out);
}

// Round 11
// 2750.962 us; speedup vs baseline: 9.4283x; 1.2970x over previous
//
#include <hip/hip_runtime.h>

#define B_ 8
#define H_ 8
#define DM 512
#define DH 64
#define LMAX 2048
#define COUT 2
#define BKP 40   // LDS row stride (shorts) for 32-k tile, +8 pad

typedef __attribute__((ext_vector_type(8))) short frag8;
typedef __attribute__((ext_vector_type(4))) float f32x4;

__device__ __forceinline__ short f2bf(float v) {
  unsigned u = __float_as_uint(v);
  unsigned r = (u + 0x7fffu + ((u >> 16) & 1u)) >> 16;   // RNE
  return (short)r;
}
__device__ __forceinline__ float bf2f(short s) {
  return __uint_as_float(((unsigned)(unsigned short)s) << 16);
}

// ---------------- JAX threefry2x32 ----------------
__device__ __forceinline__ void tf2x32(unsigned k0, unsigned k1, unsigned x0, unsigned x1,
                                       unsigned& o0, unsigned& o1) {
  unsigned ks2 = k0 ^ k1 ^ 0x1BD11BDAu;
  x0 += k0; x1 += k1;
#define RND(r) { x0 += x1; x1 = (x1 << r) | (x1 >> (32 - r)); x1 ^= x0; }
  RND(13) RND(15) RND(26) RND(6)  x0 += k1;  x1 += ks2 + 1u;
  RND(17) RND(29) RND(16) RND(24) x0 += ks2; x1 += k0 + 2u;
  RND(13) RND(15) RND(26) RND(6)  x0 += k0;  x1 += k1 + 3u;
  RND(17) RND(29) RND(16) RND(24) x0 += k1;  x1 += ks2 + 4u;
  RND(13) RND(15) RND(26) RND(6)  x0 += ks2; x1 += k0 + 5u;
#undef RND
  o0 = x0; o1 = x1;
}

// VERIFIED (R7, absmax 0.0): Variant B partitionable. DO NOT TOUCH.
__global__ void idx_kernel(int* __restrict__ idxArr, int L, int U, int layer) {
  int p = blockIdx.x * 256 + threadIdx.x;
  int half = L * U;
  if (p >= half) return;
  unsigned fk0, fk1, k20, k21, o0, o1;
  tf2x32(0u, 42u, 0u, (unsigned)layer, fk0, fk1);
  tf2x32(fk0, fk1, 0u, 1u, k20, k21);
  tf2x32(k20, k21, 0u, (unsigned)p, o0, o1);
  idxArr[p] = (int)((o0 ^ o1) & (unsigned)(L - 1));
}

// ---------------- token embed + positional encoding ----------------
__global__ void embed_kernel(const float* __restrict__ xe, const float* __restrict__ tw,
                             float* __restrict__ X) {
  int i = blockIdx.x * 256 + threadIdx.x;
  int c = i % DM;
  int l = (i / DM) % LMAX;
  int b = i / (DM * LMAX);
  int lm = (l + LMAX - 1) & (LMAX - 1);
  int lp = (l + 1) & (LMAX - 1);
  const float* xb = xe + b * LMAX;
  float tok = tw[c * 3 + 0] * xb[lm] + tw[c * 3 + 1] * xb[l] + tw[c * 3 + 2] * xb[lp];
  float freq = expf(-(float)(c & ~1) * (9.210340371976184f / 512.0f));
  float ang = (float)l * freq;
  float pe = (c & 1) ? cosf(ang) : sinf(ang);
  X[i] = tok + pe;
}

// ---------------- bf16x3-split MFMA GEMM: C[M,512] (+)= A @ W^T + bias ----------------
// BM=BN=128, BK=32, 4 waves (2x2 of 64x64). f32-equivalent accuracy (8 of 9 split
// products; dropped lo*lo ~2^-32). ACT=gelu, QKV=(b,h,l,d) scatter, ACC=+=,
// CONV=3-tap circular K=1536.
template <int ACT, int QKV, int ACC, int CONV>
__global__ __launch_bounds__(256, 2) void mgemm(const float* __restrict__ A,
                                                const float* __restrict__ W,
                                                const float* __restrict__ bias,
                                                float* __restrict__ C, int L, int Ktot) {
  __shared__ short A0[128 * BKP], A1[128 * BKP], A2[128 * BKP];
  __shared__ short B0[128 * BKP], B1[128 * BKP], B2[128 * BKP];
  int tid = threadIdx.x;
  int lane = tid & 63, wave = tid >> 6;
  int n0 = blockIdx.x * 128, m0 = blockIdx.y * 128;
  int wm = (wave >> 1) * 64, wn = (wave & 1) * 64;
  f32x4 acc[4][4] = {};
  int lrow = lane & 15, lq = lane >> 4;

  for (int k0 = 0; k0 < Ktot; k0 += 32) {
    int tap = 0, kcol = k0;
    if (CONV) { tap = k0 >> 9; kcol = k0 & 511; }
#pragma unroll
    for (int it = 0; it < 4; ++it) {
      int f = tid + it * 256;            // 0..1023 float4 slots
      int r = f >> 3, kq = f & 7;
      // ---- A ----
      const float* ap;
      if (CONV) {
        int row = m0 + r;
        int b = row / L, l = row - b * L;
        int le = l + tap - 1;
        le = (le < 0) ? le + L : (le >= L ? le - L : le);
        ap = A + ((size_t)(b * L + le) * DM + kcol + kq * 4);
      } else {
        ap = A + ((size_t)(m0 + r) * DM + k0 + kq * 4);
      }
      float4 va = *(const float4*)ap;
      short4 h0, h1, h2;
      {
        float v[4] = {va.x, va.y, va.z, va.w};
        short s0[4], s1[4], s2[4];
#pragma unroll
        for (int c = 0; c < 4; ++c) {
          s0[c] = f2bf(v[c]);
          float r1 = v[c] - bf2f(s0[c]);
          s1[c] = f2bf(r1);
          float r2 = r1 - bf2f(s1[c]);
          s2[c] = f2bf(r2);
        }
        h0 = make_short4(s0[0], s0[1], s0[2], s0[3]);
        h1 = make_short4(s1[0], s1[1], s1[2], s1[3]);
        h2 = make_short4(s2[0], s2[1], s2[2], s2[3]);
      }
      int off = r * BKP + kq * 4;
      *(short4*)&A0[off] = h0;
      *(short4*)&A1[off] = h1;
      *(short4*)&A2[off] = h2;
      // ---- B (weights, row n0+r, stride Ktot) ----
      float4 vb = *(const float4*)(W + ((size_t)(n0 + r) * Ktot + k0 + kq * 4));
      {
        float v[4] = {vb.x, vb.y, vb.z, vb.w};
        short s0[4], s1[4], s2[4];
#pragma unroll
        for (int c = 0; c < 4; ++c) {
          s0[c] = f2bf(v[c]);
          float r1 = v[c] - bf2f(s0[c]);
          s1[c] = f2bf(r1);
          float r2 = r1 - bf2f(s1[c]);
          s2[c] = f2bf(r2);
        }
        h0 = make_short4(s0[0], s0[1], s0[2], s0[3]);
        h1 = make_short4(s1[0], s1[1], s1[2], s1[3]);
        h2 = make_short4(s2[0], s2[1], s2[2], s2[3]);
      }
      *(short4*)&B0[off] = h0;
      *(short4*)&B1[off] = h1;
      *(short4*)&B2[off] = h2;
    }
    __syncthreads();
    // fragments: A/B row = lane&15 (+tile), k = (lane>>4)*8 + j
    frag8 a0f[4], a1f[4], a2f[4];
#pragma unroll
    for (int ti = 0; ti < 4; ++ti) {
      int off = (wm + ti * 16 + lrow) * BKP + lq * 8;
      a0f[ti] = *(const frag8*)&A0[off];
      a1f[ti] = *(const frag8*)&A1[off];
      a2f[ti] = *(const frag8*)&A2[off];
    }
#pragma unroll
    for (int tj = 0; tj < 4; ++tj) {
      int off = (wn + tj * 16 + lrow) * BKP + lq * 8;
      frag8 b0 = *(const frag8*)&B0[off];
      frag8 b1 = *(const frag8*)&B1[off];
      frag8 b2 = *(const frag8*)&B2[off];
#pragma unroll
      for (int ti = 0; ti < 4; ++ti) {
        f32x4 ac = acc[ti][tj];
        ac = __builtin_amdgcn_mfma_f32_16x16x32_bf16(a1f[ti], b2, ac, 0, 0, 0);
        ac = __builtin_amdgcn_mfma_f32_16x16x32_bf16(a2f[ti], b1, ac, 0, 0, 0);
        ac = __builtin_amdgcn_mfma_f32_16x16x32_bf16(a0f[ti], b2, ac, 0, 0, 0);
        ac = __builtin_amdgcn_mfma_f32_16x16x32_bf16(a2f[ti], b0, ac, 0, 0, 0);
        ac = __builtin_amdgcn_mfma_f32_16x16x32_bf16(a1f[ti], b1, ac, 0, 0, 0);
        ac = __builtin_amdgcn_mfma_f32_16x16x32_bf16(a0f[ti], b1, ac, 0, 0, 0);
        ac = __builtin_amdgcn_mfma_f32_16x16x32_bf16(a1f[ti], b0, ac, 0, 0, 0);
        ac = __builtin_amdgcn_mfma_f32_16x16x32_bf16(a0f[ti], b0, ac, 0, 0, 0);
        acc[ti][tj] = ac;
      }
    }
    __syncthreads();
  }
  // epilogue: C/D map col=lane&15, row=(lane>>4)*4+reg
#pragma unroll
  for (int ti = 0; ti < 4; ++ti) {
#pragma unroll
    for (int tj = 0; tj < 4; ++tj) {
#pragma unroll
      for (int r = 0; r < 4; ++r) {
        int row = m0 + wm + ti * 16 + lq * 4 + r;
        int col = n0 + wn + tj * 16 + lrow;
        float v = acc[ti][tj][r];
        if (!CONV) v += bias[col];
        if (ACT) v = 0.5f * v * (1.0f + erff(v * 0.70710678118654752f));
        if (QKV) {
          int b = row / L, l = row - b * L;
          int h = col >> 6, d = col & 63;
          C[(((size_t)b * H_ + h) * L + l) * DH + d] = v;
        } else if (ACC) {
          C[(size_t)row * DM + col] += v;
        } else {
          C[(size_t)row * DM + col] = v;
        }
      }
    }
  }
}

// ---------------- conv weight transpose ----------------
__global__ void wt_kernel(const float* __restrict__ w, float* __restrict__ Wt) {
  int i = blockIdx.x * 256 + threadIdx.x;   // 512*1536
  int n = i / 1536, r = i - n * 1536, tap = r >> 9, k = r & 511;
  Wt[i] = w[((size_t)n * DM + k) * 3 + tap];
}

// ---------------- conv epilogue: BN + ELU ----------------
__global__ void bnelu_kernel(float* __restrict__ Y, const float* __restrict__ cb,
                             const float* __restrict__ g, const float* __restrict__ be) {
  int i = blockIdx.x * 256 + threadIdx.x;
  int c = i % DM;
  const float invs = 0.9999950000374997f;  // 1/sqrt(1+1e-5)
  float z = Y[i] + cb[c];
  z = z * invs * g[c] + be[c];
  Y[i] = z > 0.f ? z : expm1f(z);
}

// ---------------- sampled qk -> M = max_u - mean_u; 5-way ILP ----------------
__global__ void qkM_kernel(const float* __restrict__ Q, const float* __restrict__ Kd,
                           const int* __restrict__ idxArr, float* __restrict__ Mout,
                           int L, int U) {
  int lane = threadIdx.x & 63, wv = threadIdx.x >> 6;
  int row = blockIdx.x * 4 + wv;
  int l = row % L, bh = row / L;
  float qd = Q[((size_t)bh * L + l) * DH + lane];
  const float* Kb = Kd + (size_t)bh * L * DH + lane;
  const int* ip = idxArr + l * U;
  float mx = -1e30f, sm = 0.f;
  for (int u = 0; u < U; u += 5) {
    int k0 = ip[u], k1 = ip[u + 1], k2 = ip[u + 2], k3 = ip[u + 3], k4 = ip[u + 4];
    float p0 = qd * Kb[(size_t)k0 * DH];
    float p1 = qd * Kb[(size_t)k1 * DH];
    float p2 = qd * Kb[(size_t)k2 * DH];
    float p3 = qd * Kb[(size_t)k3 * DH];
    float p4 = qd * Kb[(size_t)k4 * DH];
#pragma unroll
    for (int o = 32; o >= 1; o >>= 1) {
      p0 += __shfl_xor(p0, o, 64);
      p1 += __shfl_xor(p1, o, 64);
      p2 += __shfl_xor(p2, o, 64);
      p3 += __shfl_xor(p3, o, 64);
      p4 += __shfl_xor(p4, o, 64);
    }
    mx = fmaxf(mx, fmaxf(fmaxf(p0, p1), fmaxf(fmaxf(p2, p3), p4)));
    sm += p0 + p1 + p2 + p3 + p4;
  }
  if (lane == 0) Mout[row] = mx - sm / (float)U;
}

// ---------------- top-U per bh ----------------
__global__ void topk_kernel(const float* __restrict__ M, int* __restrict__ top, int L, int U) {
  __shared__ float vals[LMAX];
  __shared__ float rv[256];
  __shared__ int ri[256];
  int bh = blockIdx.x, tid = threadIdx.x;
  for (int j = tid; j < L; j += 256) vals[j] = M[(size_t)bh * L + j];
  __syncthreads();
  for (int u = 0; u < U; ++u) {
    float bv = -1e30f; int bi = L;
    for (int j = tid; j < L; j += 256) {
      float v = vals[j];
      if (v > bv) { bv = v; bi = j; }
    }
    rv[tid] = bv; ri[tid] = bi;
    __syncthreads();
    for (int s = 128; s >= 1; s >>= 1) {
      if (tid < s) {
        float ov = rv[tid + s]; int oi = ri[tid + s];
        if (ov > rv[tid] || (ov == rv[tid] && oi < ri[tid])) { rv[tid] = ov; ri[tid] = oi; }
      }
      __syncthreads();
    }
    if (tid == 0) { top[bh * U + u] = ri[0]; vals[ri[0]] = -1e30f; }
    __syncthreads();
  }
}

// ---------------- v mean over L per (bh,d) ----------------
__global__ void vmean_kernel(const float* __restrict__ V, float* __restrict__ VM, int L) {
  __shared__ float red[256];
  int bh = blockIdx.x, tid = threadIdx.x, d = tid & 63, sq = tid >> 6;
  float s = 0.f;
  for (int l = sq; l < L; l += 4) s += V[((size_t)bh * L + l) * DH + d];
  red[tid] = s;
  __syncthreads();
  if (sq == 0) VM[bh * DH + d] = (red[d] + red[d + 64] + red[d + 128] + red[d + 192]) / (float)L;
}

// ---------------- fill ctx (g,L,DM) with v-mean ----------------
__global__ void fill_kernel(const float* __restrict__ VM, float* __restrict__ O, int L) {
  size_t i = (size_t)blockIdx.x * 256 + threadIdx.x;
  int c = (int)(i % DM);
  int b = (int)(i / ((size_t)L * DM));
  O[i] = VM[b * DM + c];
}

// ---------------- flash-style attention for selected queries ----------------
__global__ __launch_bounds__(256) void attn_fused(const float* __restrict__ Q,
                                                  const float* __restrict__ Kd,
                                                  const float* __restrict__ V,
                                                  const int* __restrict__ top,
                                                  float* __restrict__ O, int L, int U) {
  __shared__ float Qs[8][64];
  __shared__ float Kt[64][65];
  __shared__ float Vs[64][68];
  __shared__ float ps[8][64];
  __shared__ int lst[8];
  int nch = (U + 7) >> 3;
  int bh = blockIdx.x / nch, ch = blockIdx.x - bh * nch;
  int u0g = ch * 8;
  int qn = U - u0g; if (qn > 8) qn = 8;
  int tid = threadIdx.x, lane = tid & 63, wv = tid >> 6;
  if (tid < qn) lst[tid] = top[bh * U + u0g + tid];
  __syncthreads();
  for (int idx = tid; idx < qn * 64; idx += 256) {
    int u = idx >> 6, d = idx & 63;
    Qs[u][d] = Q[((size_t)bh * L + lst[u]) * DH + d];
  }
  __syncthreads();
  int ua = wv, ub = wv + 4;
  bool hasA = ua < qn, hasB = ub < qn;
  float m0 = -1e30f, l0 = 0.f, o0 = 0.f;
  float m1 = -1e30f, l1 = 0.f, o1 = 0.f;
  const float* Kbase = Kd + (size_t)bh * L * DH;
  const float* Vbase = V + (size_t)bh * L * DH;
  for (int t0 = 0; t0 < L; t0 += 64) {
#pragma unroll
    for (int it = 0; it < 4; ++it) {
      int idx = tid + it * 256;
      int j = idx >> 4, d4 = (idx & 15) * 4;
      float4 kv = *(const float4*)(Kbase + (size_t)(t0 + j) * DH + d4);
      Kt[d4 + 0][j] = kv.x; Kt[d4 + 1][j] = kv.y;
      Kt[d4 + 2][j] = kv.z; Kt[d4 + 3][j] = kv.w;
      *(float4*)&Vs[j][d4] = *(const float4*)(Vbase + (size_t)(t0 + j) * DH + d4);
    }
    __syncthreads();
    float s0 = 0.f, s1 = 0.f;
#pragma unroll 16
    for (int d = 0; d < 64; ++d) {
      float kd = Kt[d][lane];
      s0 += kd * Qs[ua & 7][d];
      s1 += kd * Qs[ub & 7][d];
    }
    s0 *= 0.125f; s1 *= 0.125f;
    if (hasA) {
      float tm = s0;
#pragma unroll
      for (int o = 32; o >= 1; o >>= 1) tm = fmaxf(tm, __shfl_xor(tm, o, 64));
      float nm = fmaxf(m0, tm);
      float alpha = expf(m0 - nm);
      float p = expf(s0 - nm);
      float tsum = p;
#pragma unroll
      for (int o = 32; o >= 1; o >>= 1) tsum += __shfl_xor(tsum, o, 64);
      l0 = l0 * alpha + tsum;
      m0 = nm;
      ps[ua][lane] = p;
      o0 *= alpha;
    }
    if (hasB) {
      float tm = s1;
#pragma unroll
      for (int o = 32; o >= 1; o >>= 1) tm = fmaxf(tm, __shfl_xor(tm, o, 64));
      float nm = fmaxf(m1, tm);
      float alpha = expf(m1 - nm);
      float p = expf(s1 - nm);
      float tsum = p;
#pragma unroll
      for (int o = 32; o >= 1; o >>= 1) tsum += __shfl_xor(tsum, o, 64);
      l1 = l1 * alpha + tsum;
      m1 = nm;
      ps[ub][lane] = p;
      o1 *= alpha;
    }
    if (hasA) {
#pragma unroll 16
      for (int j = 0; j < 64; ++j) o0 += ps[ua][j] * Vs[j][lane];
    }
    if (hasB) {
#pragma unroll 16
      for (int j = 0; j < 64; ++j) o1 += ps[ub][j] * Vs[j][lane];
    }
    __syncthreads();
  }
  int b = bh / H_, h = bh - b * H_;
  if (hasA) O[((size_t)b * L + lst[ua]) * DM + h * DH + lane] = o0 / l0;
  if (hasB) O[((size_t)b * L + lst[ub]) * DM + h * DH + lane] = o1 / l1;
}

// ---------------- x = LayerNorm(x) in place ----------------
__global__ void ln_kernel(float* __restrict__ X, const float* __restrict__ g,
                          const float* __restrict__ be) {
  __shared__ float red[256];
  int row = blockIdx.x, tid = threadIdx.x;
  size_t base = (size_t)row * DM;
  float t0 = X[base + tid];
  float t1 = X[base + tid + 256];
  red[tid] = t0 + t1;
  __syncthreads();
  for (int s = 128; s >= 1; s >>= 1) { if (tid < s) red[tid] += red[tid + s]; __syncthreads(); }
  float mu = red[0] / 512.0f;
  __syncthreads();
  float d0 = t0 - mu, d1 = t1 - mu;
  red[tid] = d0 * d0 + d1 * d1;
  __syncthreads();
  for (int s = 128; s >= 1; s >>= 1) { if (tid < s) red[tid] += red[tid + s]; __syncthreads(); }
  float rstd = 1.0f / sqrtf(red[0] / 512.0f + 1e-5f);
  X[base + tid] = d0 * rstd * g[tid] + be[tid];
  X[base + tid + 256] = d1 * rstd * g[tid + 256] + be[tid + 256];
}

// ---------------- maxpool k=3 s=2 pad=1 along L ----------------
__global__ void pool_kernel(const float* __restrict__ Y, float* __restrict__ X, int L2) {
  int i = blockIdx.x * 256 + threadIdx.x;
  int c = i % DM;
  int t = (i / DM) % L2;
  int b = i / (DM * L2);
  int L = L2 * 2;
  const float* yb = Y + (size_t)b * L * DM + c;
  float m = fmaxf(yb[(size_t)(2 * t) * DM], yb[(size_t)(2 * t + 1) * DM]);
  if (t > 0) m = fmaxf(m, yb[(size_t)(2 * t - 1) * DM]);
  X[i] = m;
}

// ---------------- column max, 2-stage ----------------
__global__ void colmax1_kernel(const float* __restrict__ X, float* __restrict__ P, int L) {
  int nlc = L >> 6;
  int bl = blockIdx.x;
  int b = bl / nlc, lc = bl % nlc;
  const float* xb = X + ((size_t)b * L + lc * 64) * DM;
  for (int c = threadIdx.x; c < DM; c += 256) {
    float m = -1e30f;
    for (int r = 0; r < 64; ++r) m = fmaxf(m, xb[(size_t)r * DM + c]);
    P[((size_t)b * nlc + lc) * DM + c] = m;
  }
}
__global__ void colmax2_kernel(const float* __restrict__ P, float* __restrict__ mc, int nlc) {
  int i = blockIdx.x * 256 + threadIdx.x;
  int b = i / DM, c = i % DM;
  float m = -1e30f;
  for (int lc = 0; lc < nlc; ++lc) m = fmaxf(m, P[((size_t)b * nlc + lc) * DM + c]);
  mc[i] = m;
}

// ---------------- final projection ----------------
__global__ void proj_kernel(const float* __restrict__ mc, const float* __restrict__ pw,
                            const float* __restrict__ pb, float* __restrict__ out) {
  __shared__ float red[256];
  int bo = blockIdx.x, b = bo / COUT, o = bo % COUT, tid = threadIdx.x;
  float s = mc[b * DM + tid] * pw[o * DM + tid] +
            mc[b * DM + tid + 256] * pw[o * DM + tid + 256];
  red[tid] = s;
  __syncthreads();
  for (int st = 128; st >= 1; st >>= 1) { if (tid < st) red[tid] += red[tid + st]; __syncthreads(); }
  if (tid == 0) out[bo] = red[0] + pb[o];
}

extern "C" void kernel_launch(void* const* d_in, const int* in_sizes, int n_in,
                              void* d_out, int out_size, void* d_ws, size_t ws_size,
                              hipStream_t stream) {
  (void)in_sizes; (void)n_in; (void)out_size;
  const float* xe   = (const float*)d_in[0];
  const float* tw   = (const float*)d_in[1];
  const float* Wq   = (const float*)d_in[2];
  const float* Wk   = (const float*)d_in[3];
  const float* Wv   = (const float*)d_in[4];
  const float* Wo   = (const float*)d_in[5];
  const float* bq   = (const float*)d_in[6];
  const float* bk   = (const float*)d_in[7];
  const float* bv   = (const float*)d_in[8];
  const float* bo   = (const float*)d_in[9];
  const float* W1   = (const float*)d_in[10];
  const float* b1   = (const float*)d_in[11];
  const float* W2   = (const float*)d_in[12];
  const float* b2   = (const float*)d_in[13];
  const float* ln1g = (const float*)d_in[14];
  const float* ln1b = (const float*)d_in[15];
  const float* ln2g = (const float*)d_in[16];
  const float* ln2b = (const float*)d_in[17];
  const float* dcw  = (const float*)d_in[18];
  const float* dcb  = (const float*)d_in[19];
  const float* bng  = (const float*)d_in[20];
  const float* bnb  = (const float*)d_in[21];
  const float* lnfg = (const float*)d_in[22];
  const float* lnfb = (const float*)d_in[23];
  const float* pw   = (const float*)d_in[24];
  const float* pb   = (const float*)d_in[25];
  float* out = (float*)d_out;

  float* Wf = (float*)d_ws;
  const size_t NB  = (size_t)B_ * LMAX * DM;
  const size_t NHB = (size_t)H_ * LMAX * DH;
  const size_t S_IDX = 81920, S_MV = 131072, S_TOP = 4096, S_VM = 4096,
               S_MC = 4096, S_P = 32768;
  const size_t SMALL = S_IDX + S_MV + S_TOP + S_VM + S_MC + S_P + 1024;

  int g = 8;
  while (g > 1 && (2 * NB + 3 * (size_t)g * NHB + SMALL) * 4 > ws_size) g >>= 1;

  float* X  = Wf;
  float* T  = X + NB;
  float* Q  = T + NB;
  float* K  = Q + (size_t)g * NHB;
  float* V  = K + (size_t)g * NHB;
  float* SM = V + (size_t)g * NHB;
  int*   IDX = (int*)SM;
  float* Mv  = SM + S_IDX;
  int*   TOP = (int*)(Mv + S_MV);
  float* VM  = Mv + S_MV + S_TOP;
  float* MC  = VM + S_VM;
  float* P   = MC + S_MC;
  float* Wt  = Q;   // Q/K/V free during conv phase

  embed_kernel<<<B_ * LMAX * DM / 256, 256, 0, stream>>>(xe, tw, X);

  int L = LMAX;
  for (int i = 0; i < 3; ++i) {
    int U = (i == 0) ? 40 : 35;
    size_t wOff = (size_t)i * DM * DM;
    int ng = B_ / g;
    int nch = (U + 7) >> 3;

    idx_kernel<<<(L * U + 255) / 256, 256, 0, stream>>>(IDX, L, U, i);

    for (int gb = 0; gb < ng; ++gb) {
      const float* Xg = X + (size_t)gb * g * L * DM;
      float* Tg = T + (size_t)gb * g * L * DM;
      dim3 gq(DM / 128, g * L / 128);
      mgemm<0, 1, 0, 0><<<gq, 256, 0, stream>>>(Xg, Wq + wOff, bq + i * DM, Q, L, DM);
      mgemm<0, 1, 0, 0><<<gq, 256, 0, stream>>>(Xg, Wk + wOff, bk + i * DM, K, L, DM);
      mgemm<0, 1, 0, 0><<<gq, 256, 0, stream>>>(Xg, Wv + wOff, bv + i * DM, V, L, DM);
      qkM_kernel<<<g * H_ * L / 4, 256, 0, stream>>>(Q, K, IDX, Mv, L, U);
      topk_kernel<<<g * H_, 256, 0, stream>>>(Mv, TOP, L, U);
      vmean_kernel<<<g * H_, 256, 0, stream>>>(V, VM, L);
      fill_kernel<<<(unsigned)((size_t)g * L * DM / 256), 256, 0, stream>>>(VM, Tg, L);
      attn_fused<<<g * H_ * nch, 256, 0, stream>>>(Q, K, V, TOP, Tg, L, U);
    }

    dim3 gf(DM / 128, B_ * L / 128);
    mgemm<0, 0, 1, 0><<<gf, 256, 0, stream>>>(T, Wo + wOff, bo + i * DM, X, L, DM);
    ln_kernel<<<B_ * L, 256, 0, stream>>>(X, ln1g + i * DM, ln1b + i * DM);
    mgemm<1, 0, 0, 0><<<gf, 256, 0, stream>>>(X, W1 + wOff, b1 + i * DM, T, L, DM);
    mgemm<0, 0, 1, 0><<<gf, 256, 0, stream>>>(T, W2 + wOff, b2 + i * DM, X, L, DM);
    ln_kernel<<<B_ * L, 256, 0, stream>>>(X, ln2g + i * DM, ln2b + i * DM);

    if (i < 2) {
      wt_kernel<<<DM * 1536 / 256, 256, 0, stream>>>(dcw + (size_t)i * DM * DM * 3, Wt);
      mgemm<0, 0, 0, 1><<<gf, 256, 0, stream>>>(X, Wt, nullptr, T, L, 1536);
      bnelu_kernel<<<B_ * L * DM / 256, 256, 0, stream>>>(T, dcb + i * DM, bng + i * DM,
                                                          bnb + i * DM);
      L >>= 1;
      pool_kernel<<<B_ * L * DM / 256, 256, 0, stream>>>(T, X, L);
    }
  }

  ln_kernel<<<B_ * L, 256, 0, stream>>>(X, lnfg, lnfb);
  colmax1_kernel<<<B_ * (L >> 6), 256, 0, stream>>>(X, P, L);
  colmax2_kernel<<<B_ * DM / 256, 256, 0, stream>>>(P, MC, L >> 6);
  proj_kernel<<<B_ * COUT, 256, 0, stream>>>(MC, pw, pb, out);
}